// Round 1
// baseline (2551.081 us; speedup 1.0000x reference)
//
#include <hip/hip_runtime.h>
#include <hip/hip_bf16.h>
#include <math.h>

#define NUM_USER 50000
#define NUM_ITEM 30000
#define N_NODES  80000
#define N_EDGES  1000000
#define FEAT_DIM 768
#define DLAT 128
#define DID  64
#define NEG_SLOPE 0.01f

__device__ __forceinline__ float leaky(float v) { return v >= 0.f ? v : NEG_SLOPE * v; }

__device__ __forceinline__ float wave_reduce_sum(float v) {
#pragma unroll
    for (int off = 32; off > 0; off >>= 1) v += __shfl_xor(v, off, 64);
    return v;
}

// ---------------- temp_features = tanh(features @ mlp_w + b) -> x[50000+item] ----------------
#define MLP_ROWS 32
__global__ __launch_bounds__(256) void mlp_tanh_kernel(
    const float* __restrict__ F, const float* __restrict__ W,
    const float* __restrict__ b, float* __restrict__ xout)
{
    __shared__ float sX[MLP_ROWS][DLAT];   // 32 rows x 128 k-chunk (16 KB)
    __shared__ float sW[DLAT][DLAT];       // 128 k x 128 cols (64 KB)
    const int tid = threadIdx.x;
    const int col = tid & 127;
    const int rh  = tid >> 7;              // 0..1
    const int row0 = blockIdx.x * MLP_ROWS;
    float acc[16];
#pragma unroll
    for (int r = 0; r < 16; r++) acc[r] = 0.f;

    for (int kc = 0; kc < FEAT_DIM; kc += 128) {
        for (int i = tid; i < 128 * 128; i += 256)
            sW[i >> 7][i & 127] = W[(size_t)(kc + (i >> 7)) * DLAT + (i & 127)];
        for (int i = tid; i < MLP_ROWS * 128; i += 256) {
            int r = i >> 7, k = i & 127;
            int gr = row0 + r;
            sX[r][k] = (gr < NUM_ITEM) ? F[(size_t)gr * FEAT_DIM + kc + k] : 0.f;
        }
        __syncthreads();
        for (int k = 0; k < 128; k++) {
            float w = sW[k][col];
#pragma unroll
            for (int r = 0; r < 16; r++) acc[r] += sX[rh * 16 + r][k] * w;
        }
        __syncthreads();
    }
    float bias = b[col];
#pragma unroll
    for (int r = 0; r < 16; r++) {
        int gr = row0 + rh * 16 + r;
        if (gr < NUM_ITEM)
            xout[(size_t)(NUM_USER + gr) * DLAT + col] = tanhf(acc[r] + bias);
    }
}

// ---------------- in-place row L2 normalize (D=128), wave per row ----------------
__global__ __launch_bounds__(256) void l2norm_rows_kernel(float* __restrict__ x)
{
    int wid = blockIdx.x * 4 + (threadIdx.x >> 6);
    if (wid >= N_NODES) return;
    int lane = threadIdx.x & 63;
    float* row = x + (size_t)wid * DLAT;
    float v0 = row[lane], v1 = row[lane + 64];
    float s = wave_reduce_sum(v0 * v0 + v1 * v1);
    float inv = 1.0f / fmaxf(sqrtf(s), 1e-12f);
    row[lane] = v0 * inv;
    row[lane + 64] = v1 * inv;
}

// ---------------- out-degree over src ----------------
__global__ __launch_bounds__(256) void deg_kernel(const int* __restrict__ src, int* __restrict__ deg)
{
    int e = blockIdx.x * 256 + threadIdx.x;
    if (e < N_EDGES) atomicAdd(&deg[src[e]], 1);
}

// ---------------- xw = x @ W (128->128), W staged in LDS, wave per node ----------------
__global__ __launch_bounds__(256) void xw128_kernel(
    const float* __restrict__ x, const float* __restrict__ W, float* __restrict__ o)
{
    __shared__ float sW[DLAT][DLAT];   // 64 KB
    const int tid = threadIdx.x;
    for (int i = tid; i < DLAT * DLAT; i += 256) sW[i >> 7][i & 127] = W[i];
    __syncthreads();
    const int lane = tid & 63;
    const int nwaves = gridDim.x * 4;
    for (int n = blockIdx.x * 4 + (tid >> 6); n < N_NODES; n += nwaves) {
        const float* row = x + (size_t)n * DLAT;
        float v0 = row[lane], v1 = row[lane + 64];
        float a0 = 0.f, a1 = 0.f;
#pragma unroll
        for (int k = 0; k < 64; k++) {
            float xv = __shfl(v0, k, 64);
            a0 += xv * sW[k][lane];
            a1 += xv * sW[k][lane + 64];
        }
#pragma unroll
        for (int k = 0; k < 64; k++) {
            float xv = __shfl(v1, k, 64);
            a0 += xv * sW[64 + k][lane];
            a1 += xv * sW[64 + k][lane + 64];
        }
        o[(size_t)n * DLAT + lane] = a0;
        o[(size_t)n * DLAT + lane + 64] = a1;
    }
}

// ---------------- xw2 = x1 @ W (64->64), x1 read strided from out[:, :64] ----------------
__global__ __launch_bounds__(256) void xw64_kernel(
    const float* __restrict__ xsrc, const float* __restrict__ W, float* __restrict__ o)
{
    __shared__ float sW[DID][DID];   // 16 KB
    const int tid = threadIdx.x;
    for (int i = tid; i < DID * DID; i += 256) sW[i >> 6][i & 63] = W[i];
    __syncthreads();
    const int lane = tid & 63;
    const int nwaves = gridDim.x * 4;
    for (int n = blockIdx.x * 4 + (tid >> 6); n < N_NODES; n += nwaves) {
        float xv = xsrc[(size_t)n * (2 * DID) + lane];
        float acc = 0.f;
#pragma unroll
        for (int k = 0; k < 64; k++) acc += __shfl(xv, k, 64) * sW[k][lane];
        o[(size_t)n * DID + lane] = acc;
    }
}

// ---------------- edge score + segment max (sortable-uint atomicMax), 16 lanes/edge ----------------
__device__ __forceinline__ unsigned int f32_to_ord(float f) {
    unsigned int u = __float_as_uint(f);
    return (u & 0x80000000u) ? ~u : (u | 0x80000000u);
}
__device__ __forceinline__ float ord_to_f32(unsigned int u) {
    return __uint_as_float((u & 0x80000000u) ? (u ^ 0x80000000u) : ~u);
}

__global__ __launch_bounds__(256) void edge_score128_kernel(
    const float* __restrict__ xw, const int* __restrict__ src, const int* __restrict__ dst,
    const int* __restrict__ deg, float* __restrict__ score, unsigned int* __restrict__ smax)
{
    int gid = blockIdx.x * 256 + threadIdx.x;
    int e = gid >> 4, sub = gid & 15;
    if (e >= N_EDGES) return;
    int s = src[e], d = dst[e];
    const float4* a = (const float4*)(xw + (size_t)s * DLAT);
    const float4* b = (const float4*)(xw + (size_t)d * DLAT);
    float4 a0 = a[sub * 2], a1 = a[sub * 2 + 1];
    float4 b0 = b[sub * 2], b1 = b[sub * 2 + 1];
    float p = a0.x * b0.x + a0.y * b0.y + a0.z * b0.z + a0.w * b0.w
            + a1.x * b1.x + a1.y * b1.y + a1.z * b1.z + a1.w * b1.w;
    p += __shfl_xor(p, 1, 64); p += __shfl_xor(p, 2, 64);
    p += __shfl_xor(p, 4, 64); p += __shfl_xor(p, 8, 64);
    if (sub == 0) {
        float dg = (float)deg[s];
        float gate = 1.0f / (1.0f + expf(-(p / sqrtf(dg))));
        float sc = p * gate;
        score[e] = sc;
        atomicMax(&smax[d], f32_to_ord(sc));
    }
}

__global__ __launch_bounds__(256) void edge_score64_kernel(
    const float* __restrict__ xw, const int* __restrict__ src, const int* __restrict__ dst,
    const int* __restrict__ deg, float* __restrict__ score, unsigned int* __restrict__ smax)
{
    int gid = blockIdx.x * 256 + threadIdx.x;
    int e = gid >> 4, sub = gid & 15;
    if (e >= N_EDGES) return;
    int s = src[e], d = dst[e];
    float4 a0 = ((const float4*)(xw + (size_t)s * DID))[sub];
    float4 b0 = ((const float4*)(xw + (size_t)d * DID))[sub];
    float p = a0.x * b0.x + a0.y * b0.y + a0.z * b0.z + a0.w * b0.w;
    p += __shfl_xor(p, 1, 64); p += __shfl_xor(p, 2, 64);
    p += __shfl_xor(p, 4, 64); p += __shfl_xor(p, 8, 64);
    if (sub == 0) {
        float dg = (float)deg[s];
        float gate = 1.0f / (1.0f + expf(-(p / sqrtf(dg))));
        float sc = p * gate;
        score[e] = sc;
        atomicMax(&smax[d], f32_to_ord(sc));
    }
}

// ---------------- e = exp(score - smax[dst]); denom[dst] += e ----------------
__global__ __launch_bounds__(256) void edge_exp_kernel(
    const int* __restrict__ dst, const unsigned int* __restrict__ smax,
    float* __restrict__ score, float* __restrict__ denom)
{
    int e = blockIdx.x * 256 + threadIdx.x;
    if (e >= N_EDGES) return;
    int d = dst[e];
    float m = ord_to_f32(smax[d]);
    float ev = expf(score[e] - m);
    score[e] = ev;
    atomicAdd(&denom[d], ev);
}

// ---------------- scatter: gat[dst] += xw[src] * alpha ----------------
__global__ void scatter128_kernel(
    const float* __restrict__ xw, const int* __restrict__ src, const int* __restrict__ dst,
    const float* __restrict__ e_val, const float* __restrict__ denom, float* __restrict__ gat)
{
    int e = blockIdx.x;
    int s = src[e], d = dst[e];
    float alpha = e_val[e] / (denom[d] + 1e-16f);
    int t = threadIdx.x;  // 128
    atomicAdd(&gat[(size_t)d * DLAT + t], xw[(size_t)s * DLAT + t] * alpha);
}

__global__ void scatter64_kernel(
    const float* __restrict__ xw, const int* __restrict__ src, const int* __restrict__ dst,
    const float* __restrict__ e_val, const float* __restrict__ denom, float* __restrict__ gat)
{
    int e = blockIdx.x;
    int s = src[e], d = dst[e];
    float alpha = e_val[e] / (denom[d] + 1e-16f);
    int t = threadIdx.x;  // 64
    atomicAdd(&gat[(size_t)d * DID + t], xw[(size_t)s * DID + t] * alpha);
}

// ---------------- combine layer 1: h=leaky(l2norm(gat)); x1=leaky(h@g1+b + leaky(x@lin1+b)+id) ----------------
__global__ __launch_bounds__(256) void combine1_kernel(
    const float* __restrict__ gat, const float* __restrict__ x,
    const float* __restrict__ lin_w, const float* __restrict__ lin_b,
    const float* __restrict__ g_w, const float* __restrict__ g_b,
    const float* __restrict__ id_emb, float* __restrict__ out)
{
    __shared__ float sL[DLAT][DID];   // 32 KB
    __shared__ float sG[DLAT][DID];   // 32 KB
    const int tid = threadIdx.x;
    for (int i = tid; i < DLAT * DID; i += 256) { sL[i >> 6][i & 63] = lin_w[i]; sG[i >> 6][i & 63] = g_w[i]; }
    __syncthreads();
    const int lane = tid & 63;
    const int nwaves = gridDim.x * 4;
    const float lb = lin_b[lane], gb = g_b[lane];
    for (int n = blockIdx.x * 4 + (tid >> 6); n < N_NODES; n += nwaves) {
        const float* grow = gat + (size_t)n * DLAT;
        float g0 = grow[lane], g1v = grow[lane + 64];
        float ss = wave_reduce_sum(g0 * g0 + g1v * g1v);
        float inv = 1.0f / fmaxf(sqrtf(ss), 1e-12f);
        float h0 = leaky(g0 * inv), h1 = leaky(g1v * inv);
        const float* xrow = x + (size_t)n * DLAT;
        float x0 = xrow[lane], x1v = xrow[lane + 64];
        float accL = 0.f, accG = 0.f;
#pragma unroll
        for (int k = 0; k < 64; k++) {
            accL += __shfl(x0, k, 64) * sL[k][lane];
            accG += __shfl(h0, k, 64) * sG[k][lane];
        }
#pragma unroll
        for (int k = 0; k < 64; k++) {
            accL += __shfl(x1v, k, 64) * sL[64 + k][lane];
            accG += __shfl(h1, k, 64) * sG[64 + k][lane];
        }
        float xh = leaky(accL + lb) + id_emb[(size_t)n * DID + lane];
        float x1 = leaky(accG + gb + xh);
        out[(size_t)n * (2 * DID) + lane] = x1;
    }
}

// ---------------- combine layer 2 ----------------
__global__ __launch_bounds__(256) void combine2_kernel(
    const float* __restrict__ gat, const float* __restrict__ x1src,
    const float* __restrict__ lin_w, const float* __restrict__ lin_b,
    const float* __restrict__ g_w, const float* __restrict__ g_b,
    const float* __restrict__ id_emb, float* __restrict__ out)
{
    __shared__ float sL[DID][DID];   // 16 KB
    __shared__ float sG[DID][DID];   // 16 KB
    const int tid = threadIdx.x;
    for (int i = tid; i < DID * DID; i += 256) { sL[i >> 6][i & 63] = lin_w[i]; sG[i >> 6][i & 63] = g_w[i]; }
    __syncthreads();
    const int lane = tid & 63;
    const int nwaves = gridDim.x * 4;
    const float lb = lin_b[lane], gb = g_b[lane];
    for (int n = blockIdx.x * 4 + (tid >> 6); n < N_NODES; n += nwaves) {
        float g0 = gat[(size_t)n * DID + lane];
        float ss = wave_reduce_sum(g0 * g0);
        float inv = 1.0f / fmaxf(sqrtf(ss), 1e-12f);
        float h = leaky(g0 * inv);
        float xv = x1src[(size_t)n * (2 * DID) + lane];
        float accL = 0.f, accG = 0.f;
#pragma unroll
        for (int k = 0; k < 64; k++) {
            accL += __shfl(xv, k, 64) * sL[k][lane];
            accG += __shfl(h, k, 64) * sG[k][lane];
        }
        float xh = leaky(accL + lb) + id_emb[(size_t)n * DID + lane];
        float x2 = leaky(accG + gb + xh);
        out[(size_t)n * (2 * DID) + DID + lane] = x2;
    }
}

extern "C" void kernel_launch(void* const* d_in, const int* in_sizes, int n_in,
                              void* d_out, int out_size, void* d_ws, size_t ws_size,
                              hipStream_t stream)
{
    const float* features = (const float*)d_in[0];
    const float* id_emb   = (const float*)d_in[1];
    const int*   ei       = (const int*)d_in[2];
    const float* pref     = (const float*)d_in[3];
    const float* mlp_w    = (const float*)d_in[4];
    const float* mlp_b    = (const float*)d_in[5];
    const float* conv1_w  = (const float*)d_in[6];
    const float* lin1_w   = (const float*)d_in[7];
    const float* lin1_b   = (const float*)d_in[8];
    const float* g1_w     = (const float*)d_in[9];
    const float* g1_b     = (const float*)d_in[10];
    const float* conv2_w  = (const float*)d_in[11];
    const float* lin2_w   = (const float*)d_in[12];
    const float* lin2_b   = (const float*)d_in[13];
    const float* g2_w     = (const float*)d_in[14];
    const float* g2_b     = (const float*)d_in[15];
    const int* src = ei;
    const int* dst = ei + N_EDGES;
    float* out = (float*)d_out;

    // workspace layout (~128 MB total)
    float* x     = (float*)d_ws;                       // [80000,128]
    float* xw    = x   + (size_t)N_NODES * DLAT;       // [80000,128]
    float* gat   = xw  + (size_t)N_NODES * DLAT;       // [80000,128]
    float* score = gat + (size_t)N_NODES * DLAT;       // [1e6]
    int* deg     = (int*)(score + N_EDGES);            // [80000]
    unsigned int* smax = (unsigned int*)(deg + N_NODES);
    float* denom = (float*)(smax + N_NODES);

    // x = concat(preference, tanh(features@mlp_w+b)); l2norm rows
    hipMemcpyAsync(x, pref, (size_t)NUM_USER * DLAT * sizeof(float),
                   hipMemcpyDeviceToDevice, stream);
    hipMemsetAsync(deg, 0, N_NODES * sizeof(int), stream);
    mlp_tanh_kernel<<<(NUM_ITEM + MLP_ROWS - 1) / MLP_ROWS, 256, 0, stream>>>(features, mlp_w, mlp_b, x);
    l2norm_rows_kernel<<<(N_NODES + 3) / 4, 256, 0, stream>>>(x);
    deg_kernel<<<(N_EDGES + 255) / 256, 256, 0, stream>>>(src, deg);

    // ---- GAT layer 1 (D=128) ----
    xw128_kernel<<<512, 256, 0, stream>>>(x, conv1_w, xw);
    hipMemsetAsync(smax, 0, N_NODES * 4, stream);
    edge_score128_kernel<<<(N_EDGES * 16 + 255) / 256, 256, 0, stream>>>(xw, src, dst, deg, score, smax);
    hipMemsetAsync(denom, 0, N_NODES * 4, stream);
    edge_exp_kernel<<<(N_EDGES + 255) / 256, 256, 0, stream>>>(dst, smax, score, denom);
    hipMemsetAsync(gat, 0, (size_t)N_NODES * DLAT * 4, stream);
    scatter128_kernel<<<N_EDGES, 128, 0, stream>>>(xw, src, dst, score, denom, gat);
    combine1_kernel<<<512, 256, 0, stream>>>(gat, x, lin1_w, lin1_b, g1_w, g1_b, id_emb, out);

    // ---- GAT layer 2 (D=64); x1 lives in out[:, :64] ----
    xw64_kernel<<<512, 256, 0, stream>>>(out, conv2_w, xw);
    hipMemsetAsync(smax, 0, N_NODES * 4, stream);
    edge_score64_kernel<<<(N_EDGES * 16 + 255) / 256, 256, 0, stream>>>(xw, src, dst, deg, score, smax);
    hipMemsetAsync(denom, 0, N_NODES * 4, stream);
    edge_exp_kernel<<<(N_EDGES + 255) / 256, 256, 0, stream>>>(dst, smax, score, denom);
    hipMemsetAsync(gat, 0, (size_t)N_NODES * DID * 4, stream);
    scatter64_kernel<<<N_EDGES, 64, 0, stream>>>(xw, src, dst, score, denom, gat);
    combine2_kernel<<<512, 256, 0, stream>>>(gat, out, lin2_w, lin2_b, g2_w, g2_b, id_emb, out);
}

// Round 2
// 1319.501 us; speedup vs baseline: 1.9334x; 1.9334x over previous
//
#include <hip/hip_runtime.h>
#include <hip/hip_bf16.h>
#include <math.h>

#define NUM_USER 50000
#define NUM_ITEM 30000
#define N_NODES  80000
#define N_EDGES  1000000
#define FEAT_DIM 768
#define DLAT 128
#define DID  64
#define NEG_SLOPE 0.01f

__device__ __forceinline__ float leaky(float v) { return v >= 0.f ? v : NEG_SLOPE * v; }

__device__ __forceinline__ float wave_reduce_sum(float v) {
#pragma unroll
    for (int off = 32; off > 0; off >>= 1) v += __shfl_xor(v, off, 64);
    return v;
}

// =======================================================================
// Generic register-tiled GEMM: O[r][c] = act(sum_k A[r*lda+k] * W[k*N+c] + b[c])
// 256 threads, 64-row tile, thread computes 4 rows x (N/16) cols.
// K chunked at 64.  ACT: 0=none, 1=tanh
// =======================================================================
template<int K_TOTAL, int N_COLS, int ACT, bool HAS_BIAS>
__global__ __launch_bounds__(256) void gemm_kernel(
    const float* __restrict__ A, int lda,
    const float* __restrict__ W, const float* __restrict__ bias,
    float* __restrict__ O, int ldo, int rows)
{
    constexpr int KC = 64;
    constexpr int CT = N_COLS / 16;           // cols per thread (8 or 4)
    __shared__ float sW[KC * N_COLS];         // 32KB (N=128) / 16KB (N=64)
    __shared__ float sX[64][KC + 4];          // ~17KB

    const int tid = threadIdx.x;
    const int ty = tid >> 4;                  // 0..15 -> rows ty*4..+3
    const int tx = tid & 15;                  // cols tx*CT..
    const int r0 = blockIdx.x * 64;

    float acc[4][CT];
#pragma unroll
    for (int i = 0; i < 4; i++)
#pragma unroll
        for (int c = 0; c < CT; c++) acc[i][c] = 0.f;

    for (int kc = 0; kc < K_TOTAL; kc += KC) {
        // --- stage W chunk (contiguous rows) ---
        const float4* Wc = (const float4*)(W + (size_t)kc * N_COLS);
        for (int i = tid; i < KC * N_COLS / 4; i += 256)
            ((float4*)sW)[i] = Wc[i];
        // --- stage A tile: thread loads 16 floats of one row ---
        {
            int row = tid >> 2, q = tid & 3;
            int gr = r0 + row;
            float4 v[4];
            if (gr < rows) {
                const float4* Ar = (const float4*)(A + (size_t)gr * lda + kc);
#pragma unroll
                for (int i = 0; i < 4; i++) v[i] = Ar[q * 4 + i];
            } else {
#pragma unroll
                for (int i = 0; i < 4; i++) v[i] = make_float4(0.f, 0.f, 0.f, 0.f);
            }
#pragma unroll
            for (int i = 0; i < 4; i++)
                *(float4*)&sX[row][q * 16 + i * 4] = v[i];
        }
        __syncthreads();

        for (int k = 0; k < KC; k++) {
            float xv[4];
#pragma unroll
            for (int i = 0; i < 4; i++) xv[i] = sX[ty * 4 + i][k];
            float4 w0 = *(const float4*)&sW[k * N_COLS + tx * CT];
            if (CT == 8) {
                float4 w1 = *(const float4*)&sW[k * N_COLS + tx * CT + 4];
#pragma unroll
                for (int i = 0; i < 4; i++) {
                    acc[i][0] += xv[i] * w0.x; acc[i][1] += xv[i] * w0.y;
                    acc[i][2] += xv[i] * w0.z; acc[i][3] += xv[i] * w0.w;
                    acc[i][4] += xv[i] * w1.x; acc[i][5] += xv[i] * w1.y;
                    acc[i][6] += xv[i] * w1.z; acc[i][7] += xv[i] * w1.w;
                }
            } else {
#pragma unroll
                for (int i = 0; i < 4; i++) {
                    acc[i][0] += xv[i] * w0.x; acc[i][1] += xv[i] * w0.y;
                    acc[i][2] += xv[i] * w0.z; acc[i][3] += xv[i] * w0.w;
                }
            }
        }
        __syncthreads();
    }

    // --- epilogue ---
#pragma unroll
    for (int i = 0; i < 4; i++) {
        int gr = r0 + ty * 4 + i;
        if (gr >= rows) continue;
#pragma unroll
        for (int c = 0; c < CT; c++) {
            int col = tx * CT + c;
            float v = acc[i][c];
            if (HAS_BIAS) v += bias[col];
            if (ACT == 1) v = tanhf(v);
            O[(size_t)gr * ldo + col] = v;
        }
    }
}

// =======================================================================
// Fused combine: out[n][out_off+c] =
//   leaky( h@g_w + g_b + leaky(x@lin_w + lin_b) + id_emb )
// H dense [N][K]; X row-stride ldx (first K cols used). N fixed 80000 (64|80000).
// =======================================================================
template<int K>
__global__ __launch_bounds__(256) void combine_gemm_kernel(
    const float* __restrict__ H,
    const float* __restrict__ X, int ldx,
    const float* __restrict__ g_w, const float* __restrict__ g_b,
    const float* __restrict__ lin_w, const float* __restrict__ lin_b,
    const float* __restrict__ id_emb,
    float* __restrict__ out, int out_off)
{
    constexpr int KC = 64;
    __shared__ float sWg[KC * DID];       // 16KB
    __shared__ float sWl[KC * DID];       // 16KB
    __shared__ float sH[64][KC + 4];      // ~17KB
    __shared__ float sX[64][KC + 4];      // ~17KB

    const int tid = threadIdx.x;
    const int ty = tid >> 4;
    const int tx = tid & 15;
    const int r0 = blockIdx.x * 64;

    float accG[4][4], accL[4][4];
#pragma unroll
    for (int i = 0; i < 4; i++)
#pragma unroll
        for (int c = 0; c < 4; c++) { accG[i][c] = 0.f; accL[i][c] = 0.f; }

    for (int kc = 0; kc < K; kc += KC) {
        const float4* Wg = (const float4*)(g_w + (size_t)kc * DID);
        const float4* Wl = (const float4*)(lin_w + (size_t)kc * DID);
        for (int i = tid; i < KC * DID / 4; i += 256) {
            ((float4*)sWg)[i] = Wg[i];
            ((float4*)sWl)[i] = Wl[i];
        }
        {
            int row = tid >> 2, q = tid & 3;
            int gr = r0 + row;
            const float4* Hr = (const float4*)(H + (size_t)gr * K + kc);
            const float4* Xr = (const float4*)(X + (size_t)gr * ldx + kc);
#pragma unroll
            for (int i = 0; i < 4; i++) {
                *(float4*)&sH[row][q * 16 + i * 4] = Hr[q * 4 + i];
                *(float4*)&sX[row][q * 16 + i * 4] = Xr[q * 4 + i];
            }
        }
        __syncthreads();

        for (int k = 0; k < KC; k++) {
            float hv[4], xv[4];
#pragma unroll
            for (int i = 0; i < 4; i++) { hv[i] = sH[ty * 4 + i][k]; xv[i] = sX[ty * 4 + i][k]; }
            float4 wg = *(const float4*)&sWg[k * DID + tx * 4];
            float4 wl = *(const float4*)&sWl[k * DID + tx * 4];
#pragma unroll
            for (int i = 0; i < 4; i++) {
                accG[i][0] += hv[i] * wg.x; accG[i][1] += hv[i] * wg.y;
                accG[i][2] += hv[i] * wg.z; accG[i][3] += hv[i] * wg.w;
                accL[i][0] += xv[i] * wl.x; accL[i][1] += xv[i] * wl.y;
                accL[i][2] += xv[i] * wl.z; accL[i][3] += xv[i] * wl.w;
            }
        }
        __syncthreads();
    }

#pragma unroll
    for (int i = 0; i < 4; i++) {
        int gr = r0 + ty * 4 + i;
#pragma unroll
        for (int c = 0; c < 4; c++) {
            int col = tx * 4 + c;
            float xh = leaky(accL[i][c] + lin_b[col]) + id_emb[(size_t)gr * DID + col];
            float v = leaky(accG[i][c] + g_b[col] + xh);
            out[(size_t)gr * (2 * DID) + out_off + col] = v;
        }
    }
}

// ---------------- in-place row L2 normalize (D=128), wave per row ----------------
__global__ __launch_bounds__(256) void l2norm_rows_kernel(float* __restrict__ x)
{
    int wid = blockIdx.x * 4 + (threadIdx.x >> 6);
    if (wid >= N_NODES) return;
    int lane = threadIdx.x & 63;
    float* row = x + (size_t)wid * DLAT;
    float v0 = row[lane], v1 = row[lane + 64];
    float s = wave_reduce_sum(v0 * v0 + v1 * v1);
    float inv = 1.0f / fmaxf(sqrtf(s), 1e-12f);
    row[lane] = v0 * inv;
    row[lane + 64] = v1 * inv;
}

// ---------------- h = leaky(l2norm(gat)) in-place, D=128 / D=64 ----------------
__global__ __launch_bounds__(256) void h128_kernel(float* __restrict__ g)
{
    int wid = blockIdx.x * 4 + (threadIdx.x >> 6);
    if (wid >= N_NODES) return;
    int lane = threadIdx.x & 63;
    float* row = g + (size_t)wid * DLAT;
    float v0 = row[lane], v1 = row[lane + 64];
    float s = wave_reduce_sum(v0 * v0 + v1 * v1);
    float inv = 1.0f / fmaxf(sqrtf(s), 1e-12f);
    row[lane] = leaky(v0 * inv);
    row[lane + 64] = leaky(v1 * inv);
}

__global__ __launch_bounds__(256) void h64_kernel(float* __restrict__ g)
{
    int wid = blockIdx.x * 4 + (threadIdx.x >> 6);
    if (wid >= N_NODES) return;
    int lane = threadIdx.x & 63;
    float* row = g + (size_t)wid * DID;
    float v = row[lane];
    float s = wave_reduce_sum(v * v);
    float inv = 1.0f / fmaxf(sqrtf(s), 1e-12f);
    row[lane] = leaky(v * inv);
}

// ---------------- out-degree over src ----------------
__global__ __launch_bounds__(256) void deg_kernel(const int* __restrict__ src, int* __restrict__ deg)
{
    int e = blockIdx.x * 256 + threadIdx.x;
    if (e < N_EDGES) atomicAdd(&deg[src[e]], 1);
}

// ---------------- edge score + segment max ----------------
__device__ __forceinline__ unsigned int f32_to_ord(float f) {
    unsigned int u = __float_as_uint(f);
    return (u & 0x80000000u) ? ~u : (u | 0x80000000u);
}
__device__ __forceinline__ float ord_to_f32(unsigned int u) {
    return __uint_as_float((u & 0x80000000u) ? (u ^ 0x80000000u) : ~u);
}

__global__ __launch_bounds__(256) void edge_score128_kernel(
    const float* __restrict__ xw, const int* __restrict__ src, const int* __restrict__ dst,
    const int* __restrict__ deg, float* __restrict__ score, unsigned int* __restrict__ smax)
{
    int gid = blockIdx.x * 256 + threadIdx.x;
    int e = gid >> 4, sub = gid & 15;
    if (e >= N_EDGES) return;
    int s = src[e], d = dst[e];
    const float4* a = (const float4*)(xw + (size_t)s * DLAT);
    const float4* b = (const float4*)(xw + (size_t)d * DLAT);
    float4 a0 = a[sub * 2], a1 = a[sub * 2 + 1];
    float4 b0 = b[sub * 2], b1 = b[sub * 2 + 1];
    float p = a0.x * b0.x + a0.y * b0.y + a0.z * b0.z + a0.w * b0.w
            + a1.x * b1.x + a1.y * b1.y + a1.z * b1.z + a1.w * b1.w;
    p += __shfl_xor(p, 1, 64); p += __shfl_xor(p, 2, 64);
    p += __shfl_xor(p, 4, 64); p += __shfl_xor(p, 8, 64);
    if (sub == 0) {
        float dg = (float)deg[s];
        float gate = 1.0f / (1.0f + expf(-(p / sqrtf(dg))));
        float sc = p * gate;
        score[e] = sc;
        atomicMax(&smax[d], f32_to_ord(sc));
    }
}

__global__ __launch_bounds__(256) void edge_score64_kernel(
    const float* __restrict__ xw, const int* __restrict__ src, const int* __restrict__ dst,
    const int* __restrict__ deg, float* __restrict__ score, unsigned int* __restrict__ smax)
{
    int gid = blockIdx.x * 256 + threadIdx.x;
    int e = gid >> 4, sub = gid & 15;
    if (e >= N_EDGES) return;
    int s = src[e], d = dst[e];
    float4 a0 = ((const float4*)(xw + (size_t)s * DID))[sub];
    float4 b0 = ((const float4*)(xw + (size_t)d * DID))[sub];
    float p = a0.x * b0.x + a0.y * b0.y + a0.z * b0.z + a0.w * b0.w;
    p += __shfl_xor(p, 1, 64); p += __shfl_xor(p, 2, 64);
    p += __shfl_xor(p, 4, 64); p += __shfl_xor(p, 8, 64);
    if (sub == 0) {
        float dg = (float)deg[s];
        float gate = 1.0f / (1.0f + expf(-(p / sqrtf(dg))));
        float sc = p * gate;
        score[e] = sc;
        atomicMax(&smax[d], f32_to_ord(sc));
    }
}

// ---------------- e = exp(score - smax[dst]); denom[dst] += e ----------------
__global__ __launch_bounds__(256) void edge_exp_kernel(
    const int* __restrict__ dst, const unsigned int* __restrict__ smax,
    float* __restrict__ score, float* __restrict__ denom)
{
    int e = blockIdx.x * 256 + threadIdx.x;
    if (e >= N_EDGES) return;
    int d = dst[e];
    float m = ord_to_f32(smax[d]);
    float ev = expf(score[e] - m);
    score[e] = ev;
    atomicAdd(&denom[d], ev);
}

// ---------------- scatter: gat[dst] += xw[src] * alpha ----------------
__global__ void scatter128_kernel(
    const float* __restrict__ xw, const int* __restrict__ src, const int* __restrict__ dst,
    const float* __restrict__ e_val, const float* __restrict__ denom, float* __restrict__ gat)
{
    int e = blockIdx.x;
    int s = src[e], d = dst[e];
    float alpha = e_val[e] / (denom[d] + 1e-16f);
    int t = threadIdx.x;  // 128
    atomicAdd(&gat[(size_t)d * DLAT + t], xw[(size_t)s * DLAT + t] * alpha);
}

__global__ void scatter64_kernel(
    const float* __restrict__ xw, const int* __restrict__ src, const int* __restrict__ dst,
    const float* __restrict__ e_val, const float* __restrict__ denom, float* __restrict__ gat)
{
    int e = blockIdx.x;
    int s = src[e], d = dst[e];
    float alpha = e_val[e] / (denom[d] + 1e-16f);
    int t = threadIdx.x;  // 64
    atomicAdd(&gat[(size_t)d * DID + t], xw[(size_t)s * DID + t] * alpha);
}

extern "C" void kernel_launch(void* const* d_in, const int* in_sizes, int n_in,
                              void* d_out, int out_size, void* d_ws, size_t ws_size,
                              hipStream_t stream)
{
    const float* features = (const float*)d_in[0];
    const float* id_emb   = (const float*)d_in[1];
    const int*   ei       = (const int*)d_in[2];
    const float* pref     = (const float*)d_in[3];
    const float* mlp_w    = (const float*)d_in[4];
    const float* mlp_b    = (const float*)d_in[5];
    const float* conv1_w  = (const float*)d_in[6];
    const float* lin1_w   = (const float*)d_in[7];
    const float* lin1_b   = (const float*)d_in[8];
    const float* g1_w     = (const float*)d_in[9];
    const float* g1_b     = (const float*)d_in[10];
    const float* conv2_w  = (const float*)d_in[11];
    const float* lin2_w   = (const float*)d_in[12];
    const float* lin2_b   = (const float*)d_in[13];
    const float* g2_w     = (const float*)d_in[14];
    const float* g2_b     = (const float*)d_in[15];
    const int* src = ei;
    const int* dst = ei + N_EDGES;
    float* out = (float*)d_out;

    // workspace layout
    float* x     = (float*)d_ws;                       // [80000,128]
    float* xw    = x   + (size_t)N_NODES * DLAT;       // [80000,128]
    float* gat   = xw  + (size_t)N_NODES * DLAT;       // [80000,128] (also holds h in-place)
    float* score = gat + (size_t)N_NODES * DLAT;       // [1e6]
    int* deg     = (int*)(score + N_EDGES);            // [80000]
    unsigned int* smax = (unsigned int*)(deg + N_NODES);
    float* denom = (float*)(smax + N_NODES);

    // x = concat(preference, tanh(features@mlp_w+b)); l2norm rows
    hipMemcpyAsync(x, pref, (size_t)NUM_USER * DLAT * sizeof(float),
                   hipMemcpyDeviceToDevice, stream);
    hipMemsetAsync(deg, 0, N_NODES * sizeof(int), stream);
    gemm_kernel<FEAT_DIM, DLAT, 1, true><<<(NUM_ITEM + 63) / 64, 256, 0, stream>>>(
        features, FEAT_DIM, mlp_w, mlp_b, x + (size_t)NUM_USER * DLAT, DLAT, NUM_ITEM);
    l2norm_rows_kernel<<<(N_NODES + 3) / 4, 256, 0, stream>>>(x);
    deg_kernel<<<(N_EDGES + 255) / 256, 256, 0, stream>>>(src, deg);

    // ---- GAT layer 1 (D=128) ----
    gemm_kernel<DLAT, DLAT, 0, false><<<N_NODES / 64, 256, 0, stream>>>(
        x, DLAT, conv1_w, nullptr, xw, DLAT, N_NODES);
    hipMemsetAsync(smax, 0, N_NODES * 4, stream);
    edge_score128_kernel<<<(N_EDGES * 16 + 255) / 256, 256, 0, stream>>>(xw, src, dst, deg, score, smax);
    hipMemsetAsync(denom, 0, N_NODES * 4, stream);
    edge_exp_kernel<<<(N_EDGES + 255) / 256, 256, 0, stream>>>(dst, smax, score, denom);
    hipMemsetAsync(gat, 0, (size_t)N_NODES * DLAT * 4, stream);
    scatter128_kernel<<<N_EDGES, 128, 0, stream>>>(xw, src, dst, score, denom, gat);
    h128_kernel<<<(N_NODES + 3) / 4, 256, 0, stream>>>(gat);
    combine_gemm_kernel<DLAT><<<N_NODES / 64, 256, 0, stream>>>(
        gat, x, DLAT, g1_w, g1_b, lin1_w, lin1_b, id_emb, out, 0);

    // ---- GAT layer 2 (D=64); x1 lives in out[:, :64] ----
    gemm_kernel<DID, DID, 0, false><<<N_NODES / 64, 256, 0, stream>>>(
        out, 2 * DID, conv2_w, nullptr, xw, DID, N_NODES);
    hipMemsetAsync(smax, 0, N_NODES * 4, stream);
    edge_score64_kernel<<<(N_EDGES * 16 + 255) / 256, 256, 0, stream>>>(xw, src, dst, deg, score, smax);
    hipMemsetAsync(denom, 0, N_NODES * 4, stream);
    edge_exp_kernel<<<(N_EDGES + 255) / 256, 256, 0, stream>>>(dst, smax, score, denom);
    hipMemsetAsync(gat, 0, (size_t)N_NODES * DID * 4, stream);
    scatter64_kernel<<<N_EDGES, 64, 0, stream>>>(xw, src, dst, score, denom, gat);
    h64_kernel<<<(N_NODES + 3) / 4, 256, 0, stream>>>(gat);
    combine_gemm_kernel<DID><<<N_NODES / 64, 256, 0, stream>>>(
        gat, out, 2 * DID, g2_w, g2_b, lin2_w, lin2_b, id_emb, out, DID);
}

// Round 3
// 926.538 us; speedup vs baseline: 2.7533x; 1.4241x over previous
//
#include <hip/hip_runtime.h>
#include <hip/hip_bf16.h>
#include <math.h>

#define NUM_USER 50000
#define NUM_ITEM 30000
#define N_NODES  80000
#define N_EDGES  1000000
#define FEAT_DIM 768
#define DLAT 128
#define DID  64
#define NEG_SLOPE 0.01f

__device__ __forceinline__ float leaky(float v) { return v >= 0.f ? v : NEG_SLOPE * v; }

__device__ __forceinline__ float wave_reduce_sum(float v) {
#pragma unroll
    for (int off = 32; off > 0; off >>= 1) v += __shfl_xor(v, off, 64);
    return v;
}

// =======================================================================
// Generic register-tiled GEMM: O[r][c] = act(sum_k A[r*lda+k] * W[k*N+c] + b[c])
// 256 threads, 64-row tile, thread computes 4 rows x (N/16) cols. K chunked at 64.
// ACT: 0=none, 1=tanh
// =======================================================================
template<int K_TOTAL, int N_COLS, int ACT, bool HAS_BIAS>
__global__ __launch_bounds__(256) void gemm_kernel(
    const float* __restrict__ A, int lda,
    const float* __restrict__ W, const float* __restrict__ bias,
    float* __restrict__ O, int ldo, int rows)
{
    constexpr int KC = 64;
    constexpr int CT = N_COLS / 16;
    __shared__ float sW[KC * N_COLS];
    __shared__ float sX[64][KC + 4];

    const int tid = threadIdx.x;
    const int ty = tid >> 4;
    const int tx = tid & 15;
    const int r0 = blockIdx.x * 64;

    float acc[4][CT];
#pragma unroll
    for (int i = 0; i < 4; i++)
#pragma unroll
        for (int c = 0; c < CT; c++) acc[i][c] = 0.f;

    for (int kc = 0; kc < K_TOTAL; kc += KC) {
        const float4* Wc = (const float4*)(W + (size_t)kc * N_COLS);
        for (int i = tid; i < KC * N_COLS / 4; i += 256)
            ((float4*)sW)[i] = Wc[i];
        {
            int row = tid >> 2, q = tid & 3;
            int gr = r0 + row;
            float4 v[4];
            if (gr < rows) {
                const float4* Ar = (const float4*)(A + (size_t)gr * lda + kc);
#pragma unroll
                for (int i = 0; i < 4; i++) v[i] = Ar[q * 4 + i];
            } else {
#pragma unroll
                for (int i = 0; i < 4; i++) v[i] = make_float4(0.f, 0.f, 0.f, 0.f);
            }
#pragma unroll
            for (int i = 0; i < 4; i++)
                *(float4*)&sX[row][q * 16 + i * 4] = v[i];
        }
        __syncthreads();

        for (int k = 0; k < KC; k++) {
            float xv[4];
#pragma unroll
            for (int i = 0; i < 4; i++) xv[i] = sX[ty * 4 + i][k];
            float4 w0 = *(const float4*)&sW[k * N_COLS + tx * CT];
            if (CT == 8) {
                float4 w1 = *(const float4*)&sW[k * N_COLS + tx * CT + 4];
#pragma unroll
                for (int i = 0; i < 4; i++) {
                    acc[i][0] += xv[i] * w0.x; acc[i][1] += xv[i] * w0.y;
                    acc[i][2] += xv[i] * w0.z; acc[i][3] += xv[i] * w0.w;
                    acc[i][4] += xv[i] * w1.x; acc[i][5] += xv[i] * w1.y;
                    acc[i][6] += xv[i] * w1.z; acc[i][7] += xv[i] * w1.w;
                }
            } else {
#pragma unroll
                for (int i = 0; i < 4; i++) {
                    acc[i][0] += xv[i] * w0.x; acc[i][1] += xv[i] * w0.y;
                    acc[i][2] += xv[i] * w0.z; acc[i][3] += xv[i] * w0.w;
                }
            }
        }
        __syncthreads();
    }

#pragma unroll
    for (int i = 0; i < 4; i++) {
        int gr = r0 + ty * 4 + i;
        if (gr >= rows) continue;
#pragma unroll
        for (int c = 0; c < CT; c++) {
            int col = tx * CT + c;
            float v = acc[i][c];
            if (HAS_BIAS) v += bias[col];
            if (ACT == 1) v = tanhf(v);
            O[(size_t)gr * ldo + col] = v;
        }
    }
}

// =======================================================================
// Fused combine: out[n][out_off+c] = leaky(h@g_w + g_b + leaky(x@lin_w + lin_b) + id)
// =======================================================================
template<int K>
__global__ __launch_bounds__(256) void combine_gemm_kernel(
    const float* __restrict__ H,
    const float* __restrict__ X, int ldx,
    const float* __restrict__ g_w, const float* __restrict__ g_b,
    const float* __restrict__ lin_w, const float* __restrict__ lin_b,
    const float* __restrict__ id_emb,
    float* __restrict__ out, int out_off)
{
    constexpr int KC = 64;
    __shared__ float sWg[KC * DID];
    __shared__ float sWl[KC * DID];
    __shared__ float sH[64][KC + 4];
    __shared__ float sX[64][KC + 4];

    const int tid = threadIdx.x;
    const int ty = tid >> 4;
    const int tx = tid & 15;
    const int r0 = blockIdx.x * 64;

    float accG[4][4], accL[4][4];
#pragma unroll
    for (int i = 0; i < 4; i++)
#pragma unroll
        for (int c = 0; c < 4; c++) { accG[i][c] = 0.f; accL[i][c] = 0.f; }

    for (int kc = 0; kc < K; kc += KC) {
        const float4* Wg = (const float4*)(g_w + (size_t)kc * DID);
        const float4* Wl = (const float4*)(lin_w + (size_t)kc * DID);
        for (int i = tid; i < KC * DID / 4; i += 256) {
            ((float4*)sWg)[i] = Wg[i];
            ((float4*)sWl)[i] = Wl[i];
        }
        {
            int row = tid >> 2, q = tid & 3;
            int gr = r0 + row;
            const float4* Hr = (const float4*)(H + (size_t)gr * K + kc);
            const float4* Xr = (const float4*)(X + (size_t)gr * ldx + kc);
#pragma unroll
            for (int i = 0; i < 4; i++) {
                *(float4*)&sH[row][q * 16 + i * 4] = Hr[q * 4 + i];
                *(float4*)&sX[row][q * 16 + i * 4] = Xr[q * 4 + i];
            }
        }
        __syncthreads();

        for (int k = 0; k < KC; k++) {
            float hv[4], xv[4];
#pragma unroll
            for (int i = 0; i < 4; i++) { hv[i] = sH[ty * 4 + i][k]; xv[i] = sX[ty * 4 + i][k]; }
            float4 wg = *(const float4*)&sWg[k * DID + tx * 4];
            float4 wl = *(const float4*)&sWl[k * DID + tx * 4];
#pragma unroll
            for (int i = 0; i < 4; i++) {
                accG[i][0] += hv[i] * wg.x; accG[i][1] += hv[i] * wg.y;
                accG[i][2] += hv[i] * wg.z; accG[i][3] += hv[i] * wg.w;
                accL[i][0] += xv[i] * wl.x; accL[i][1] += xv[i] * wl.y;
                accL[i][2] += xv[i] * wl.z; accL[i][3] += xv[i] * wl.w;
            }
        }
        __syncthreads();
    }

#pragma unroll
    for (int i = 0; i < 4; i++) {
        int gr = r0 + ty * 4 + i;
#pragma unroll
        for (int c = 0; c < 4; c++) {
            int col = tx * 4 + c;
            float xh = leaky(accL[i][c] + lin_b[col]) + id_emb[(size_t)gr * DID + col];
            float v = leaky(accG[i][c] + g_b[col] + xh);
            out[(size_t)gr * (2 * DID) + out_off + col] = v;
        }
    }
}

// ---------------- in-place row L2 normalize (D=128), wave per row ----------------
__global__ __launch_bounds__(256) void l2norm_rows_kernel(float* __restrict__ x)
{
    int wid = blockIdx.x * 4 + (threadIdx.x >> 6);
    if (wid >= N_NODES) return;
    int lane = threadIdx.x & 63;
    float* row = x + (size_t)wid * DLAT;
    float v0 = row[lane], v1 = row[lane + 64];
    float s = wave_reduce_sum(v0 * v0 + v1 * v1);
    float inv = 1.0f / fmaxf(sqrtf(s), 1e-12f);
    row[lane] = v0 * inv;
    row[lane + 64] = v1 * inv;
}

// ---------------- degree count: out-degree (src) + in-degree (dst) ----------------
__global__ __launch_bounds__(256) void count_kernel(
    const int* __restrict__ src, const int* __restrict__ dst,
    int* __restrict__ deg_out, int* __restrict__ cnt_in)
{
    int e = blockIdx.x * 256 + threadIdx.x;
    if (e < N_EDGES) {
        atomicAdd(&deg_out[src[e]], 1);
        atomicAdd(&cnt_in[dst[e]], 1);
    }
}

// ---------------- exclusive scan of cnt_in[80000] -> rowptr[80001], one block ----------------
#define SCAN_T 1024
__global__ __launch_bounds__(SCAN_T) void scan_kernel(
    const int* __restrict__ cnt, int* __restrict__ rowptr)
{
    __shared__ int part[SCAN_T];
    const int CHUNK = (N_NODES + SCAN_T - 1) / SCAN_T;  // 79
    int t = threadIdx.x;
    int begin = t * CHUNK;
    int end = min(begin + CHUNK, N_NODES);
    int s = 0;
    for (int i = begin; i < end; i++) s += cnt[i];
    part[t] = s;
    __syncthreads();
    for (int off = 1; off < SCAN_T; off <<= 1) {
        int u = (t >= off) ? part[t - off] : 0;
        __syncthreads();
        part[t] += u;
        __syncthreads();
    }
    int run = (t > 0) ? part[t - 1] : 0;   // exclusive prefix
    for (int i = begin; i < end; i++) {
        rowptr[i] = run;
        run += cnt[i];
    }
    if (end == N_NODES && begin <= N_NODES) rowptr[N_NODES] = run;
}

// ---------------- CSR fill: csr_src[slot] = src[e] grouped by dst ----------------
__global__ __launch_bounds__(256) void csr_fill_kernel(
    const int* __restrict__ src, const int* __restrict__ dst,
    const int* __restrict__ rowptr, int* __restrict__ cursor, int* __restrict__ csr_src)
{
    int e = blockIdx.x * 256 + threadIdx.x;
    if (e < N_EDGES) {
        int d = dst[e];
        int slot = rowptr[d] + atomicAdd(&cursor[d], 1);
        csr_src[slot] = src[e];
    }
}

// =======================================================================
// Fused GAT layer: per dst node (one wave), online-softmax over incoming
// edges, accumulate alpha-weighted xw[src], then h = leaky(l2norm(.)).
// D=128: lane owns cols {2*lane, 2*lane+1}; D=64: lane owns col lane.
// =======================================================================
template<int D>
__global__ __launch_bounds__(256) void gat_layer_kernel(
    const float* __restrict__ xw, const int* __restrict__ rowptr,
    const int* __restrict__ csr_src, const int* __restrict__ deg_out,
    float* __restrict__ h)
{
    int wid = blockIdx.x * 4 + (threadIdx.x >> 6);
    if (wid >= N_NODES) return;
    int lane = threadIdx.x & 63;
    int start = rowptr[wid], end = rowptr[wid + 1];

    float xd0, xd1 = 0.f;
    if (D == 128) {
        float2 v = *(const float2*)(xw + (size_t)wid * D + 2 * lane);
        xd0 = v.x; xd1 = v.y;
    } else {
        xd0 = xw[(size_t)wid * D + lane];
    }

    float m = -INFINITY, l = 0.f, acc0 = 0.f, acc1 = 0.f;
    for (int i = start; i < end; i++) {
        int s = csr_src[i];
        float a0, a1 = 0.f;
        if (D == 128) {
            float2 v = *(const float2*)(xw + (size_t)s * D + 2 * lane);
            a0 = v.x; a1 = v.y;
        } else {
            a0 = xw[(size_t)s * D + lane];
        }
        float p = wave_reduce_sum(a0 * xd0 + a1 * xd1);
        float dg = (float)deg_out[s];
        float gate = 1.0f / (1.0f + expf(-(p / sqrtf(dg))));
        float sc = p * gate;
        float mnew = fmaxf(m, sc);
        float scale = expf(m - mnew);     // first iter: exp(-inf)=0
        float w = expf(sc - mnew);
        l = l * scale + w;
        acc0 = acc0 * scale + w * a0;
        acc1 = acc1 * scale + w * a1;
        m = mnew;
    }
    float invl = 1.0f / (l + 1e-16f);
    acc0 *= invl; acc1 *= invl;

    float ss = acc0 * acc0 + (D == 128 ? acc1 * acc1 : 0.f);
    ss = wave_reduce_sum(ss);
    float inv = 1.0f / fmaxf(sqrtf(ss), 1e-12f);
    if (D == 128) {
        float2 o; o.x = leaky(acc0 * inv); o.y = leaky(acc1 * inv);
        *(float2*)(h + (size_t)wid * D + 2 * lane) = o;
    } else {
        h[(size_t)wid * D + lane] = leaky(acc0 * inv);
    }
}

extern "C" void kernel_launch(void* const* d_in, const int* in_sizes, int n_in,
                              void* d_out, int out_size, void* d_ws, size_t ws_size,
                              hipStream_t stream)
{
    const float* features = (const float*)d_in[0];
    const float* id_emb   = (const float*)d_in[1];
    const int*   ei       = (const int*)d_in[2];
    const float* pref     = (const float*)d_in[3];
    const float* mlp_w    = (const float*)d_in[4];
    const float* mlp_b    = (const float*)d_in[5];
    const float* conv1_w  = (const float*)d_in[6];
    const float* lin1_w   = (const float*)d_in[7];
    const float* lin1_b   = (const float*)d_in[8];
    const float* g1_w     = (const float*)d_in[9];
    const float* g1_b     = (const float*)d_in[10];
    const float* conv2_w  = (const float*)d_in[11];
    const float* lin2_w   = (const float*)d_in[12];
    const float* lin2_b   = (const float*)d_in[13];
    const float* g2_w     = (const float*)d_in[14];
    const float* g2_b     = (const float*)d_in[15];
    const int* src = ei;
    const int* dst = ei + N_EDGES;
    float* out = (float*)d_out;

    // workspace layout (~128 MB)
    float* x       = (float*)d_ws;                         // [80000,128]
    float* xw      = x   + (size_t)N_NODES * DLAT;         // [80000,128]
    float* gat     = xw  + (size_t)N_NODES * DLAT;         // [80000,128] holds h
    int*   deg_out = (int*)(gat + (size_t)N_NODES * DLAT); // [80000]
    int*   cnt     = deg_out + N_NODES;                    // [80000] (count, then cursor)
    int*   rowptr  = cnt + N_NODES;                        // [80001]
    int*   csr_src = rowptr + N_NODES + 1;                 // [1e6]

    // ---- CSR build (shared by both layers) ----
    hipMemsetAsync(deg_out, 0, N_NODES * sizeof(int), stream);
    hipMemsetAsync(cnt, 0, N_NODES * sizeof(int), stream);
    count_kernel<<<(N_EDGES + 255) / 256, 256, 0, stream>>>(src, dst, deg_out, cnt);
    scan_kernel<<<1, SCAN_T, 0, stream>>>(cnt, rowptr);
    hipMemsetAsync(cnt, 0, N_NODES * sizeof(int), stream);
    csr_fill_kernel<<<(N_EDGES + 255) / 256, 256, 0, stream>>>(src, dst, rowptr, cnt, csr_src);

    // ---- x = l2norm(concat(preference, tanh(features@mlp_w+b))) ----
    hipMemcpyAsync(x, pref, (size_t)NUM_USER * DLAT * sizeof(float),
                   hipMemcpyDeviceToDevice, stream);
    gemm_kernel<FEAT_DIM, DLAT, 1, true><<<(NUM_ITEM + 63) / 64, 256, 0, stream>>>(
        features, FEAT_DIM, mlp_w, mlp_b, x + (size_t)NUM_USER * DLAT, DLAT, NUM_ITEM);
    l2norm_rows_kernel<<<(N_NODES + 3) / 4, 256, 0, stream>>>(x);

    // ---- GAT layer 1 (D=128) ----
    gemm_kernel<DLAT, DLAT, 0, false><<<N_NODES / 64, 256, 0, stream>>>(
        x, DLAT, conv1_w, nullptr, xw, DLAT, N_NODES);
    gat_layer_kernel<DLAT><<<(N_NODES + 3) / 4, 256, 0, stream>>>(
        xw, rowptr, csr_src, deg_out, gat);
    combine_gemm_kernel<DLAT><<<N_NODES / 64, 256, 0, stream>>>(
        gat, x, DLAT, g1_w, g1_b, lin1_w, lin1_b, id_emb, out, 0);

    // ---- GAT layer 2 (D=64); x1 lives in out[:, :64] ----
    gemm_kernel<DID, DID, 0, false><<<N_NODES / 64, 256, 0, stream>>>(
        out, 2 * DID, conv2_w, nullptr, xw, DID, N_NODES);
    gat_layer_kernel<DID><<<(N_NODES + 3) / 4, 256, 0, stream>>>(
        xw, rowptr, csr_src, deg_out, gat);
    combine_gemm_kernel<DID><<<N_NODES / 64, 256, 0, stream>>>(
        gat, out, 2 * DID, g2_w, g2_b, lin2_w, lin2_b, id_emb, out, DID);
}

// Round 4
// 685.956 us; speedup vs baseline: 3.7190x; 1.3507x over previous
//
#include <hip/hip_runtime.h>
#include <hip/hip_bf16.h>
#include <math.h>

#define NUM_USER 50000
#define NUM_ITEM 30000
#define N_NODES  80000
#define N_EDGES  1000000
#define FEAT_DIM 768
#define DLAT 128
#define DID  64
#define NEG_SLOPE 0.01f

__device__ __forceinline__ float leaky(float v) { return v >= 0.f ? v : NEG_SLOPE * v; }

__device__ __forceinline__ float wave_reduce_sum(float v) {
#pragma unroll
    for (int off = 32; off > 0; off >>= 1) v += __shfl_xor(v, off, 64);
    return v;
}

// =======================================================================
// Generic register-tiled GEMM: O[r][c] = act(sum_k A[r*lda+k] * W[k*N+c] + b[c])
// 256 threads, 64-row tile, thread computes 4 rows x (N/16) cols. K chunked at 64.
// ACT: 0=none, 1=tanh
// =======================================================================
template<int K_TOTAL, int N_COLS, int ACT, bool HAS_BIAS>
__global__ __launch_bounds__(256) void gemm_kernel(
    const float* __restrict__ A, int lda,
    const float* __restrict__ W, const float* __restrict__ bias,
    float* __restrict__ O, int ldo, int rows)
{
    constexpr int KC = 64;
    constexpr int CT = N_COLS / 16;
    __shared__ float sW[KC * N_COLS];
    __shared__ float sX[64][KC + 4];

    const int tid = threadIdx.x;
    const int ty = tid >> 4;
    const int tx = tid & 15;
    const int r0 = blockIdx.x * 64;

    float acc[4][CT];
#pragma unroll
    for (int i = 0; i < 4; i++)
#pragma unroll
        for (int c = 0; c < CT; c++) acc[i][c] = 0.f;

    for (int kc = 0; kc < K_TOTAL; kc += KC) {
        const float4* Wc = (const float4*)(W + (size_t)kc * N_COLS);
        for (int i = tid; i < KC * N_COLS / 4; i += 256)
            ((float4*)sW)[i] = Wc[i];
        {
            int row = tid >> 2, q = tid & 3;
            int gr = r0 + row;
            float4 v[4];
            if (gr < rows) {
                const float4* Ar = (const float4*)(A + (size_t)gr * lda + kc);
#pragma unroll
                for (int i = 0; i < 4; i++) v[i] = Ar[q * 4 + i];
            } else {
#pragma unroll
                for (int i = 0; i < 4; i++) v[i] = make_float4(0.f, 0.f, 0.f, 0.f);
            }
#pragma unroll
            for (int i = 0; i < 4; i++)
                *(float4*)&sX[row][q * 16 + i * 4] = v[i];
        }
        __syncthreads();

        for (int k = 0; k < KC; k++) {
            float xv[4];
#pragma unroll
            for (int i = 0; i < 4; i++) xv[i] = sX[ty * 4 + i][k];
            float4 w0 = *(const float4*)&sW[k * N_COLS + tx * CT];
            if (CT == 8) {
                float4 w1 = *(const float4*)&sW[k * N_COLS + tx * CT + 4];
#pragma unroll
                for (int i = 0; i < 4; i++) {
                    acc[i][0] += xv[i] * w0.x; acc[i][1] += xv[i] * w0.y;
                    acc[i][2] += xv[i] * w0.z; acc[i][3] += xv[i] * w0.w;
                    acc[i][4] += xv[i] * w1.x; acc[i][5] += xv[i] * w1.y;
                    acc[i][6] += xv[i] * w1.z; acc[i][7] += xv[i] * w1.w;
                }
            } else {
#pragma unroll
                for (int i = 0; i < 4; i++) {
                    acc[i][0] += xv[i] * w0.x; acc[i][1] += xv[i] * w0.y;
                    acc[i][2] += xv[i] * w0.z; acc[i][3] += xv[i] * w0.w;
                }
            }
        }
        __syncthreads();
    }

#pragma unroll
    for (int i = 0; i < 4; i++) {
        int gr = r0 + ty * 4 + i;
        if (gr >= rows) continue;
#pragma unroll
        for (int c = 0; c < CT; c++) {
            int col = tx * CT + c;
            float v = acc[i][c];
            if (HAS_BIAS) v += bias[col];
            if (ACT == 1) v = tanhf(v);
            O[(size_t)gr * ldo + col] = v;
        }
    }
}

// =======================================================================
// Fused combine: out[n][out_off+c] = leaky(h@g_w + g_b + leaky(x@lin_w + lin_b) + id)
// =======================================================================
template<int K>
__global__ __launch_bounds__(256) void combine_gemm_kernel(
    const float* __restrict__ H,
    const float* __restrict__ X, int ldx,
    const float* __restrict__ g_w, const float* __restrict__ g_b,
    const float* __restrict__ lin_w, const float* __restrict__ lin_b,
    const float* __restrict__ id_emb,
    float* __restrict__ out, int out_off)
{
    constexpr int KC = 64;
    __shared__ float sWg[KC * DID];
    __shared__ float sWl[KC * DID];
    __shared__ float sH[64][KC + 4];
    __shared__ float sX[64][KC + 4];

    const int tid = threadIdx.x;
    const int ty = tid >> 4;
    const int tx = tid & 15;
    const int r0 = blockIdx.x * 64;

    float accG[4][4], accL[4][4];
#pragma unroll
    for (int i = 0; i < 4; i++)
#pragma unroll
        for (int c = 0; c < 4; c++) { accG[i][c] = 0.f; accL[i][c] = 0.f; }

    for (int kc = 0; kc < K; kc += KC) {
        const float4* Wg = (const float4*)(g_w + (size_t)kc * DID);
        const float4* Wl = (const float4*)(lin_w + (size_t)kc * DID);
        for (int i = tid; i < KC * DID / 4; i += 256) {
            ((float4*)sWg)[i] = Wg[i];
            ((float4*)sWl)[i] = Wl[i];
        }
        {
            int row = tid >> 2, q = tid & 3;
            int gr = r0 + row;
            const float4* Hr = (const float4*)(H + (size_t)gr * K + kc);
            const float4* Xr = (const float4*)(X + (size_t)gr * ldx + kc);
#pragma unroll
            for (int i = 0; i < 4; i++) {
                *(float4*)&sH[row][q * 16 + i * 4] = Hr[q * 4 + i];
                *(float4*)&sX[row][q * 16 + i * 4] = Xr[q * 4 + i];
            }
        }
        __syncthreads();

        for (int k = 0; k < KC; k++) {
            float hv[4], xv[4];
#pragma unroll
            for (int i = 0; i < 4; i++) { hv[i] = sH[ty * 4 + i][k]; xv[i] = sX[ty * 4 + i][k]; }
            float4 wg = *(const float4*)&sWg[k * DID + tx * 4];
            float4 wl = *(const float4*)&sWl[k * DID + tx * 4];
#pragma unroll
            for (int i = 0; i < 4; i++) {
                accG[i][0] += hv[i] * wg.x; accG[i][1] += hv[i] * wg.y;
                accG[i][2] += hv[i] * wg.z; accG[i][3] += hv[i] * wg.w;
                accL[i][0] += xv[i] * wl.x; accL[i][1] += xv[i] * wl.y;
                accL[i][2] += xv[i] * wl.z; accL[i][3] += xv[i] * wl.w;
            }
        }
        __syncthreads();
    }

#pragma unroll
    for (int i = 0; i < 4; i++) {
        int gr = r0 + ty * 4 + i;
#pragma unroll
        for (int c = 0; c < 4; c++) {
            int col = tx * 4 + c;
            float xh = leaky(accL[i][c] + lin_b[col]) + id_emb[(size_t)gr * DID + col];
            float v = leaky(accG[i][c] + g_b[col] + xh);
            out[(size_t)gr * (2 * DID) + out_off + col] = v;
        }
    }
}

// ---------------- in-place row L2 normalize (D=128), wave per row ----------------
__global__ __launch_bounds__(256) void l2norm_rows_kernel(float* __restrict__ x)
{
    int wid = blockIdx.x * 4 + (threadIdx.x >> 6);
    if (wid >= N_NODES) return;
    int lane = threadIdx.x & 63;
    float* row = x + (size_t)wid * DLAT;
    float v0 = row[lane], v1 = row[lane + 64];
    float s = wave_reduce_sum(v0 * v0 + v1 * v1);
    float inv = 1.0f / fmaxf(sqrtf(s), 1e-12f);
    row[lane] = v0 * inv;
    row[lane + 64] = v1 * inv;
}

// ---------------- degree count: out-degree (src) + in-degree (dst) ----------------
__global__ __launch_bounds__(256) void count_kernel(
    const int* __restrict__ src, const int* __restrict__ dst,
    int* __restrict__ deg_out, int* __restrict__ cnt_in)
{
    int e = blockIdx.x * 256 + threadIdx.x;
    if (e < N_EDGES) {
        atomicAdd(&deg_out[src[e]], 1);
        atomicAdd(&cnt_in[dst[e]], 1);
    }
}

// ---------------- exclusive scan of cnt_in[80000] -> rowptr[80001], one block ----------------
#define SCAN_T 1024
__global__ __launch_bounds__(SCAN_T) void scan_kernel(
    const int* __restrict__ cnt, int* __restrict__ rowptr)
{
    __shared__ int part[SCAN_T];
    const int CHUNK = (N_NODES + SCAN_T - 1) / SCAN_T;
    int t = threadIdx.x;
    int begin = t * CHUNK;
    int end = min(begin + CHUNK, N_NODES);
    int s = 0;
    for (int i = begin; i < end; i++) s += cnt[i];
    part[t] = s;
    __syncthreads();
    for (int off = 1; off < SCAN_T; off <<= 1) {
        int u = (t >= off) ? part[t - off] : 0;
        __syncthreads();
        part[t] += u;
        __syncthreads();
    }
    int run = (t > 0) ? part[t - 1] : 0;
    for (int i = begin; i < end; i++) {
        rowptr[i] = run;
        run += cnt[i];
    }
    if (end == N_NODES && begin <= N_NODES) rowptr[N_NODES] = run;
}

// ---------------- CSR fill: csr_src[slot] = src[e] grouped by dst ----------------
__global__ __launch_bounds__(256) void csr_fill_kernel(
    const int* __restrict__ src, const int* __restrict__ dst,
    const int* __restrict__ rowptr, int* __restrict__ cursor, int* __restrict__ csr_src)
{
    int e = blockIdx.x * 256 + threadIdx.x;
    if (e < N_EDGES) {
        int d = dst[e];
        int slot = rowptr[d] + atomicAdd(&cursor[d], 1);
        csr_src[slot] = src[e];
    }
}

// ---------------- rsq_deg[n] = rsqrt(deg_out[n]) (written over freed cursor buf) ----------------
__global__ __launch_bounds__(256) void deg_rsqrt_kernel(
    const int* __restrict__ deg_out, float* __restrict__ rsq)
{
    int n = blockIdx.x * 256 + threadIdx.x;
    if (n < N_NODES) rsq[n] = rsqrtf((float)deg_out[n]);
}

// =======================================================================
// Fused GAT layer, subgroup-parallel edges.
// D=128: 4 subgroups x 16 lanes, 4 edges/chunk. D=64: 8 x 8, 8 edges/chunk.
// Lane owns 8 contiguous cols [8t, 8t+8). Each subgroup runs an independent
// online-softmax state over its edge subset; states merged at the end
// (softmax merge is order-independent). Sentinel -1e30 (finite) avoids
// exp(inf-inf) NaNs for empty rows / invalid slots.
// =======================================================================
template<int D>
__global__ __launch_bounds__(256) void gat_layer_kernel(
    const float* __restrict__ xw, const int* __restrict__ rowptr,
    const int* __restrict__ csr_src, const float* __restrict__ rsq_deg,
    float* __restrict__ h)
{
    constexpr int SG  = D / 8;    // lanes per subgroup: 16 (D=128) / 8 (D=64)
    constexpr int EPC = 64 / SG;  // edges per chunk:     4          / 8
    int wid = blockIdx.x * 4 + (threadIdx.x >> 6);
    if (wid >= N_NODES) return;
    const int lane = threadIdx.x & 63;
    const int g = lane / SG;
    const int t = lane % SG;
    const int start = rowptr[wid], end = rowptr[wid + 1];

    const float* xdp = xw + (size_t)wid * D + 8 * t;
    float4 xd0 = *(const float4*)(xdp);
    float4 xd1 = *(const float4*)(xdp + 4);

    float m = -1e30f, l = 0.f;
    float acc[8];
#pragma unroll
    for (int c = 0; c < 8; c++) acc[c] = 0.f;

    for (int base = start; base < end; base += EPC) {
        int i = base + g;
        bool valid = (i < end);
        int s = valid ? csr_src[i] : 0;
        const float* row = xw + (size_t)s * D + 8 * t;
        float4 a0 = *(const float4*)(row);
        float4 a1 = *(const float4*)(row + 4);
        float p = a0.x * xd0.x + a0.y * xd0.y + a0.z * xd0.z + a0.w * xd0.w
                + a1.x * xd1.x + a1.y * xd1.y + a1.z * xd1.z + a1.w * xd1.w;
#pragma unroll
        for (int off = SG / 2; off > 0; off >>= 1) p += __shfl_xor(p, off, 64);
        float rsd = valid ? rsq_deg[s] : 1.f;
        float gate = 1.0f / (1.0f + __expf(-(p * rsd)));
        float sc = valid ? p * gate : -1e30f;
        float mnew = fmaxf(m, sc);
        float scale = __expf(m - mnew);
        float w = valid ? __expf(sc - mnew) : 0.f;
        l = l * scale + w;
        acc[0] = acc[0] * scale + w * a0.x;
        acc[1] = acc[1] * scale + w * a0.y;
        acc[2] = acc[2] * scale + w * a0.z;
        acc[3] = acc[3] * scale + w * a0.w;
        acc[4] = acc[4] * scale + w * a1.x;
        acc[5] = acc[5] * scale + w * a1.y;
        acc[6] = acc[6] * scale + w * a1.z;
        acc[7] = acc[7] * scale + w * a1.w;
        m = mnew;
    }

    // merge subgroup states
#pragma unroll
    for (int off = SG; off < 64; off <<= 1) {
        float mo = __shfl_xor(m, off, 64);
        float lo = __shfl_xor(l, off, 64);
        float mnew = fmaxf(m, mo);
        float s1 = __expf(m - mnew), s2 = __expf(mo - mnew);
        l = l * s1 + lo * s2;
#pragma unroll
        for (int c = 0; c < 8; c++) {
            float ao = __shfl_xor(acc[c], off, 64);
            acc[c] = acc[c] * s1 + ao * s2;
        }
        m = mnew;
    }

    float invl = 1.0f / (l + 1e-16f);
    float ss = 0.f;
#pragma unroll
    for (int c = 0; c < 8; c++) { acc[c] *= invl; ss += acc[c] * acc[c]; }
#pragma unroll
    for (int off = SG / 2; off > 0; off >>= 1) ss += __shfl_xor(ss, off, 64);
    float inv = 1.0f / fmaxf(sqrtf(ss), 1e-12f);

    if (g == 0) {
        float4 o0, o1;
        o0.x = leaky(acc[0] * inv); o0.y = leaky(acc[1] * inv);
        o0.z = leaky(acc[2] * inv); o0.w = leaky(acc[3] * inv);
        o1.x = leaky(acc[4] * inv); o1.y = leaky(acc[5] * inv);
        o1.z = leaky(acc[6] * inv); o1.w = leaky(acc[7] * inv);
        float* op = h + (size_t)wid * D + 8 * t;
        *(float4*)(op) = o0;
        *(float4*)(op + 4) = o1;
    }
}

extern "C" void kernel_launch(void* const* d_in, const int* in_sizes, int n_in,
                              void* d_out, int out_size, void* d_ws, size_t ws_size,
                              hipStream_t stream)
{
    const float* features = (const float*)d_in[0];
    const float* id_emb   = (const float*)d_in[1];
    const int*   ei       = (const int*)d_in[2];
    const float* pref     = (const float*)d_in[3];
    const float* mlp_w    = (const float*)d_in[4];
    const float* mlp_b    = (const float*)d_in[5];
    const float* conv1_w  = (const float*)d_in[6];
    const float* lin1_w   = (const float*)d_in[7];
    const float* lin1_b   = (const float*)d_in[8];
    const float* g1_w     = (const float*)d_in[9];
    const float* g1_b     = (const float*)d_in[10];
    const float* conv2_w  = (const float*)d_in[11];
    const float* lin2_w   = (const float*)d_in[12];
    const float* lin2_b   = (const float*)d_in[13];
    const float* g2_w     = (const float*)d_in[14];
    const float* g2_b     = (const float*)d_in[15];
    const int* src = ei;
    const int* dst = ei + N_EDGES;
    float* out = (float*)d_out;

    // workspace layout (~128 MB)
    float* x       = (float*)d_ws;                         // [80000,128]
    float* xw      = x   + (size_t)N_NODES * DLAT;         // [80000,128]
    float* gat     = xw  + (size_t)N_NODES * DLAT;         // [80000,128] holds h
    int*   deg_out = (int*)(gat + (size_t)N_NODES * DLAT); // [80000]
    int*   cnt     = deg_out + N_NODES;                    // [80000] count->cursor->rsq_deg
    int*   rowptr  = cnt + N_NODES;                        // [80001]
    int*   csr_src = rowptr + N_NODES + 1;                 // [1e6]
    float* rsq_deg = (float*)cnt;

    // ---- CSR build (shared by both layers) ----
    hipMemsetAsync(deg_out, 0, N_NODES * sizeof(int), stream);
    hipMemsetAsync(cnt, 0, N_NODES * sizeof(int), stream);
    count_kernel<<<(N_EDGES + 255) / 256, 256, 0, stream>>>(src, dst, deg_out, cnt);
    scan_kernel<<<1, SCAN_T, 0, stream>>>(cnt, rowptr);
    hipMemsetAsync(cnt, 0, N_NODES * sizeof(int), stream);
    csr_fill_kernel<<<(N_EDGES + 255) / 256, 256, 0, stream>>>(src, dst, rowptr, cnt, csr_src);
    deg_rsqrt_kernel<<<(N_NODES + 255) / 256, 256, 0, stream>>>(deg_out, rsq_deg);

    // ---- x = l2norm(concat(preference, tanh(features@mlp_w+b))) ----
    hipMemcpyAsync(x, pref, (size_t)NUM_USER * DLAT * sizeof(float),
                   hipMemcpyDeviceToDevice, stream);
    gemm_kernel<FEAT_DIM, DLAT, 1, true><<<(NUM_ITEM + 63) / 64, 256, 0, stream>>>(
        features, FEAT_DIM, mlp_w, mlp_b, x + (size_t)NUM_USER * DLAT, DLAT, NUM_ITEM);
    l2norm_rows_kernel<<<(N_NODES + 3) / 4, 256, 0, stream>>>(x);

    // ---- GAT layer 1 (D=128) ----
    gemm_kernel<DLAT, DLAT, 0, false><<<N_NODES / 64, 256, 0, stream>>>(
        x, DLAT, conv1_w, nullptr, xw, DLAT, N_NODES);
    gat_layer_kernel<DLAT><<<(N_NODES + 3) / 4, 256, 0, stream>>>(
        xw, rowptr, csr_src, rsq_deg, gat);
    combine_gemm_kernel<DLAT><<<N_NODES / 64, 256, 0, stream>>>(
        gat, x, DLAT, g1_w, g1_b, lin1_w, lin1_b, id_emb, out, 0);

    // ---- GAT layer 2 (D=64); x1 lives in out[:, :64] ----
    gemm_kernel<DID, DID, 0, false><<<N_NODES / 64, 256, 0, stream>>>(
        out, 2 * DID, conv2_w, nullptr, xw, DID, N_NODES);
    gat_layer_kernel<DID><<<(N_NODES + 3) / 4, 256, 0, stream>>>(
        xw, rowptr, csr_src, rsq_deg, gat);
    combine_gemm_kernel<DID><<<N_NODES / 64, 256, 0, stream>>>(
        gat, out, 2 * DID, g2_w, g2_b, lin2_w, lin2_b, id_emb, out, DID);
}

// Round 5
// 565.774 us; speedup vs baseline: 4.5090x; 1.2124x over previous
//
#include <hip/hip_runtime.h>
#include <hip/hip_bf16.h>
#include <math.h>

#define NUM_USER 50000
#define NUM_ITEM 30000
#define N_NODES  80000
#define N_EDGES  1000000
#define FEAT_DIM 768
#define DLAT 128
#define DID  64
#define NEG_SLOPE 0.01f

#define SCAN_NB ((N_NODES + 255) / 256)   // 313 blocks

__device__ __forceinline__ float leaky(float v) { return v >= 0.f ? v : NEG_SLOPE * v; }

__device__ __forceinline__ float wave_reduce_sum(float v) {
#pragma unroll
    for (int off = 32; off > 0; off >>= 1) v += __shfl_xor(v, off, 64);
    return v;
}

// =======================================================================
// Generic register-tiled GEMM: O[r][c] = act(sum_k A[r*lda+k] * W[k*N+c] + b[c])
// 256 threads, 64-row tile, thread computes 4 rows x (N/16) cols. K chunked at 64.
// ACT: 0=none, 1=tanh
// =======================================================================
template<int K_TOTAL, int N_COLS, int ACT, bool HAS_BIAS>
__global__ __launch_bounds__(256) void gemm_kernel(
    const float* __restrict__ A, int lda,
    const float* __restrict__ W, const float* __restrict__ bias,
    float* __restrict__ O, int ldo, int rows)
{
    constexpr int KC = 64;
    constexpr int CT = N_COLS / 16;
    __shared__ float sW[KC * N_COLS];
    __shared__ float sX[64][KC + 4];

    const int tid = threadIdx.x;
    const int ty = tid >> 4;
    const int tx = tid & 15;
    const int r0 = blockIdx.x * 64;

    float acc[4][CT];
#pragma unroll
    for (int i = 0; i < 4; i++)
#pragma unroll
        for (int c = 0; c < CT; c++) acc[i][c] = 0.f;

    for (int kc = 0; kc < K_TOTAL; kc += KC) {
        const float4* Wc = (const float4*)(W + (size_t)kc * N_COLS);
        for (int i = tid; i < KC * N_COLS / 4; i += 256)
            ((float4*)sW)[i] = Wc[i];
        {
            int row = tid >> 2, q = tid & 3;
            int gr = r0 + row;
            float4 v[4];
            if (gr < rows) {
                const float4* Ar = (const float4*)(A + (size_t)gr * lda + kc);
#pragma unroll
                for (int i = 0; i < 4; i++) v[i] = Ar[q * 4 + i];
            } else {
#pragma unroll
                for (int i = 0; i < 4; i++) v[i] = make_float4(0.f, 0.f, 0.f, 0.f);
            }
#pragma unroll
            for (int i = 0; i < 4; i++)
                *(float4*)&sX[row][q * 16 + i * 4] = v[i];
        }
        __syncthreads();

        for (int k = 0; k < KC; k++) {
            float xv[4];
#pragma unroll
            for (int i = 0; i < 4; i++) xv[i] = sX[ty * 4 + i][k];
            float4 w0 = *(const float4*)&sW[k * N_COLS + tx * CT];
            if (CT == 8) {
                float4 w1 = *(const float4*)&sW[k * N_COLS + tx * CT + 4];
#pragma unroll
                for (int i = 0; i < 4; i++) {
                    acc[i][0] += xv[i] * w0.x; acc[i][1] += xv[i] * w0.y;
                    acc[i][2] += xv[i] * w0.z; acc[i][3] += xv[i] * w0.w;
                    acc[i][4] += xv[i] * w1.x; acc[i][5] += xv[i] * w1.y;
                    acc[i][6] += xv[i] * w1.z; acc[i][7] += xv[i] * w1.w;
                }
            } else {
#pragma unroll
                for (int i = 0; i < 4; i++) {
                    acc[i][0] += xv[i] * w0.x; acc[i][1] += xv[i] * w0.y;
                    acc[i][2] += xv[i] * w0.z; acc[i][3] += xv[i] * w0.w;
                }
            }
        }
        __syncthreads();
    }

#pragma unroll
    for (int i = 0; i < 4; i++) {
        int gr = r0 + ty * 4 + i;
        if (gr >= rows) continue;
#pragma unroll
        for (int c = 0; c < CT; c++) {
            int col = tx * CT + c;
            float v = acc[i][c];
            if (HAS_BIAS) v += bias[col];
            if (ACT == 1) v = tanhf(v);
            O[(size_t)gr * ldo + col] = v;
        }
    }
}

// =======================================================================
// Fused combine: out[n][out_off+c] = leaky(h@g_w + g_b + leaky(x@lin_w + lin_b) + id)
// =======================================================================
template<int K>
__global__ __launch_bounds__(256) void combine_gemm_kernel(
    const float* __restrict__ H,
    const float* __restrict__ X, int ldx,
    const float* __restrict__ g_w, const float* __restrict__ g_b,
    const float* __restrict__ lin_w, const float* __restrict__ lin_b,
    const float* __restrict__ id_emb,
    float* __restrict__ out, int out_off)
{
    constexpr int KC = 64;
    __shared__ float sWg[KC * DID];
    __shared__ float sWl[KC * DID];
    __shared__ float sH[64][KC + 4];
    __shared__ float sX[64][KC + 4];

    const int tid = threadIdx.x;
    const int ty = tid >> 4;
    const int tx = tid & 15;
    const int r0 = blockIdx.x * 64;

    float accG[4][4], accL[4][4];
#pragma unroll
    for (int i = 0; i < 4; i++)
#pragma unroll
        for (int c = 0; c < 4; c++) { accG[i][c] = 0.f; accL[i][c] = 0.f; }

    for (int kc = 0; kc < K; kc += KC) {
        const float4* Wg = (const float4*)(g_w + (size_t)kc * DID);
        const float4* Wl = (const float4*)(lin_w + (size_t)kc * DID);
        for (int i = tid; i < KC * DID / 4; i += 256) {
            ((float4*)sWg)[i] = Wg[i];
            ((float4*)sWl)[i] = Wl[i];
        }
        {
            int row = tid >> 2, q = tid & 3;
            int gr = r0 + row;
            const float4* Hr = (const float4*)(H + (size_t)gr * K + kc);
            const float4* Xr = (const float4*)(X + (size_t)gr * ldx + kc);
#pragma unroll
            for (int i = 0; i < 4; i++) {
                *(float4*)&sH[row][q * 16 + i * 4] = Hr[q * 4 + i];
                *(float4*)&sX[row][q * 16 + i * 4] = Xr[q * 4 + i];
            }
        }
        __syncthreads();

        for (int k = 0; k < KC; k++) {
            float hv[4], xv[4];
#pragma unroll
            for (int i = 0; i < 4; i++) { hv[i] = sH[ty * 4 + i][k]; xv[i] = sX[ty * 4 + i][k]; }
            float4 wg = *(const float4*)&sWg[k * DID + tx * 4];
            float4 wl = *(const float4*)&sWl[k * DID + tx * 4];
#pragma unroll
            for (int i = 0; i < 4; i++) {
                accG[i][0] += hv[i] * wg.x; accG[i][1] += hv[i] * wg.y;
                accG[i][2] += hv[i] * wg.z; accG[i][3] += hv[i] * wg.w;
                accL[i][0] += xv[i] * wl.x; accL[i][1] += xv[i] * wl.y;
                accL[i][2] += xv[i] * wl.z; accL[i][3] += xv[i] * wl.w;
            }
        }
        __syncthreads();
    }

#pragma unroll
    for (int i = 0; i < 4; i++) {
        int gr = r0 + ty * 4 + i;
#pragma unroll
        for (int c = 0; c < 4; c++) {
            int col = tx * 4 + c;
            float xh = leaky(accL[i][c] + lin_b[col]) + id_emb[(size_t)gr * DID + col];
            float v = leaky(accG[i][c] + g_b[col] + xh);
            out[(size_t)gr * (2 * DID) + out_off + col] = v;
        }
    }
}

// ---------------- in-place row L2 normalize (D=128), wave per row ----------------
__global__ __launch_bounds__(256) void l2norm_rows_kernel(float* __restrict__ x)
{
    int wid = blockIdx.x * 4 + (threadIdx.x >> 6);
    if (wid >= N_NODES) return;
    int lane = threadIdx.x & 63;
    float* row = x + (size_t)wid * DLAT;
    float v0 = row[lane], v1 = row[lane + 64];
    float s = wave_reduce_sum(v0 * v0 + v1 * v1);
    float inv = 1.0f / fmaxf(sqrtf(s), 1e-12f);
    row[lane] = v0 * inv;
    row[lane + 64] = v1 * inv;
}

// ---------------- degree count: out-degree (src) + in-degree (dst) ----------------
__global__ __launch_bounds__(256) void count_kernel(
    const int* __restrict__ src, const int* __restrict__ dst,
    int* __restrict__ deg_out, int* __restrict__ cnt_in)
{
    int e = blockIdx.x * 256 + threadIdx.x;
    if (e < N_EDGES) {
        atomicAdd(&deg_out[src[e]], 1);
        atomicAdd(&cnt_in[dst[e]], 1);
    }
}

// ---------------- 3-phase multi-block exclusive scan of cnt[80000] -> rowptr ----------------
// Phase A: per-block (256) exclusive scan -> rowptr (local), block total -> blocksum
__global__ __launch_bounds__(256) void scan_local_kernel(
    const int* __restrict__ cnt, int* __restrict__ rowptr, int* __restrict__ blocksum)
{
    __shared__ int wsum[4];
    int gid = blockIdx.x * 256 + threadIdx.x;
    int lane = threadIdx.x & 63, w = threadIdx.x >> 6;
    int orig = (gid < N_NODES) ? cnt[gid] : 0;
    int v = orig;
#pragma unroll
    for (int off = 1; off < 64; off <<= 1) {
        int u = __shfl_up(v, off, 64);
        if (lane >= off) v += u;
    }
    if (lane == 63) wsum[w] = v;
    __syncthreads();
    int woff = 0;
#pragma unroll
    for (int i = 0; i < 4; i++) woff += (i < w) ? wsum[i] : 0;
    if (gid < N_NODES) rowptr[gid] = v - orig + woff;   // local exclusive
    if (threadIdx.x == 255) blocksum[blockIdx.x] = woff + v;
}

// Phase B: exclusive scan of blocksum[SCAN_NB] in one 512-thread block
__global__ __launch_bounds__(512) void scan_blocksums_kernel(int* __restrict__ blocksum)
{
    __shared__ int s[512];
    int t = threadIdx.x;
    int orig = (t < SCAN_NB) ? blocksum[t] : 0;
    s[t] = orig;
    __syncthreads();
    for (int off = 1; off < 512; off <<= 1) {
        int u = (t >= off) ? s[t - off] : 0;
        __syncthreads();
        s[t] += u;
        __syncthreads();
    }
    if (t < SCAN_NB) blocksum[t] = s[t] - orig;   // exclusive
}

// Phase C: rowptr[i] += blocksum[block]; rowptr[N_NODES] = N_EDGES
__global__ __launch_bounds__(256) void scan_add_kernel(
    int* __restrict__ rowptr, const int* __restrict__ blocksum)
{
    int gid = blockIdx.x * 256 + threadIdx.x;
    if (gid < N_NODES) rowptr[gid] += blocksum[blockIdx.x];
    if (gid == 0) rowptr[N_NODES] = N_EDGES;
}

// ---------------- CSR fill: csr_src[slot] = src[e] grouped by dst ----------------
__global__ __launch_bounds__(256) void csr_fill_kernel(
    const int* __restrict__ src, const int* __restrict__ dst,
    const int* __restrict__ rowptr, int* __restrict__ cursor, int* __restrict__ csr_src)
{
    int e = blockIdx.x * 256 + threadIdx.x;
    if (e < N_EDGES) {
        int d = dst[e];
        int slot = rowptr[d] + atomicAdd(&cursor[d], 1);
        csr_src[slot] = src[e];
    }
}

// ---------------- rsq_deg[n] = rsqrt(deg_out[n]) ----------------
__global__ __launch_bounds__(256) void deg_rsqrt_kernel(
    const int* __restrict__ deg_out, float* __restrict__ rsq)
{
    int n = blockIdx.x * 256 + threadIdx.x;
    if (n < N_NODES) rsq[n] = rsqrtf((float)deg_out[n]);
}

// =======================================================================
// Fused GAT layer, subgroup-parallel edges.
// D=128: 4 subgroups x 16 lanes, 4 edges/chunk. D=64: 8 x 8, 8 edges/chunk.
// =======================================================================
template<int D>
__global__ __launch_bounds__(256) void gat_layer_kernel(
    const float* __restrict__ xw, const int* __restrict__ rowptr,
    const int* __restrict__ csr_src, const float* __restrict__ rsq_deg,
    float* __restrict__ h)
{
    constexpr int SG  = D / 8;
    constexpr int EPC = 64 / SG;
    int wid = blockIdx.x * 4 + (threadIdx.x >> 6);
    if (wid >= N_NODES) return;
    const int lane = threadIdx.x & 63;
    const int g = lane / SG;
    const int t = lane % SG;
    const int start = rowptr[wid], end = rowptr[wid + 1];

    const float* xdp = xw + (size_t)wid * D + 8 * t;
    float4 xd0 = *(const float4*)(xdp);
    float4 xd1 = *(const float4*)(xdp + 4);

    float m = -1e30f, l = 0.f;
    float acc[8];
#pragma unroll
    for (int c = 0; c < 8; c++) acc[c] = 0.f;

    for (int base = start; base < end; base += EPC) {
        int i = base + g;
        bool valid = (i < end);
        int s = valid ? csr_src[i] : 0;
        const float* row = xw + (size_t)s * D + 8 * t;
        float4 a0 = *(const float4*)(row);
        float4 a1 = *(const float4*)(row + 4);
        float p = a0.x * xd0.x + a0.y * xd0.y + a0.z * xd0.z + a0.w * xd0.w
                + a1.x * xd1.x + a1.y * xd1.y + a1.z * xd1.z + a1.w * xd1.w;
#pragma unroll
        for (int off = SG / 2; off > 0; off >>= 1) p += __shfl_xor(p, off, 64);
        float rsd = valid ? rsq_deg[s] : 1.f;
        float gate = 1.0f / (1.0f + __expf(-(p * rsd)));
        float sc = valid ? p * gate : -1e30f;
        float mnew = fmaxf(m, sc);
        float scale = __expf(m - mnew);
        float w = valid ? __expf(sc - mnew) : 0.f;
        l = l * scale + w;
        acc[0] = acc[0] * scale + w * a0.x;
        acc[1] = acc[1] * scale + w * a0.y;
        acc[2] = acc[2] * scale + w * a0.z;
        acc[3] = acc[3] * scale + w * a0.w;
        acc[4] = acc[4] * scale + w * a1.x;
        acc[5] = acc[5] * scale + w * a1.y;
        acc[6] = acc[6] * scale + w * a1.z;
        acc[7] = acc[7] * scale + w * a1.w;
        m = mnew;
    }

    // merge subgroup states
#pragma unroll
    for (int off = SG; off < 64; off <<= 1) {
        float mo = __shfl_xor(m, off, 64);
        float lo = __shfl_xor(l, off, 64);
        float mnew = fmaxf(m, mo);
        float s1 = __expf(m - mnew), s2 = __expf(mo - mnew);
        l = l * s1 + lo * s2;
#pragma unroll
        for (int c = 0; c < 8; c++) {
            float ao = __shfl_xor(acc[c], off, 64);
            acc[c] = acc[c] * s1 + ao * s2;
        }
        m = mnew;
    }

    float invl = 1.0f / (l + 1e-16f);
    float ss = 0.f;
#pragma unroll
    for (int c = 0; c < 8; c++) { acc[c] *= invl; ss += acc[c] * acc[c]; }
#pragma unroll
    for (int off = SG / 2; off > 0; off >>= 1) ss += __shfl_xor(ss, off, 64);
    float inv = 1.0f / fmaxf(sqrtf(ss), 1e-12f);

    if (g == 0) {
        float4 o0, o1;
        o0.x = leaky(acc[0] * inv); o0.y = leaky(acc[1] * inv);
        o0.z = leaky(acc[2] * inv); o0.w = leaky(acc[3] * inv);
        o1.x = leaky(acc[4] * inv); o1.y = leaky(acc[5] * inv);
        o1.z = leaky(acc[6] * inv); o1.w = leaky(acc[7] * inv);
        float* op = h + (size_t)wid * D + 8 * t;
        *(float4*)(op) = o0;
        *(float4*)(op + 4) = o1;
    }
}

extern "C" void kernel_launch(void* const* d_in, const int* in_sizes, int n_in,
                              void* d_out, int out_size, void* d_ws, size_t ws_size,
                              hipStream_t stream)
{
    const float* features = (const float*)d_in[0];
    const float* id_emb   = (const float*)d_in[1];
    const int*   ei       = (const int*)d_in[2];
    const float* pref     = (const float*)d_in[3];
    const float* mlp_w    = (const float*)d_in[4];
    const float* mlp_b    = (const float*)d_in[5];
    const float* conv1_w  = (const float*)d_in[6];
    const float* lin1_w   = (const float*)d_in[7];
    const float* lin1_b   = (const float*)d_in[8];
    const float* g1_w     = (const float*)d_in[9];
    const float* g1_b     = (const float*)d_in[10];
    const float* conv2_w  = (const float*)d_in[11];
    const float* lin2_w   = (const float*)d_in[12];
    const float* lin2_b   = (const float*)d_in[13];
    const float* g2_w     = (const float*)d_in[14];
    const float* g2_b     = (const float*)d_in[15];
    const int* src = ei;
    const int* dst = ei + N_EDGES;
    float* out = (float*)d_out;

    // workspace layout (~128 MB)
    float* x       = (float*)d_ws;                         // [80000,128]
    float* xw      = x   + (size_t)N_NODES * DLAT;         // [80000,128]
    float* gat     = xw  + (size_t)N_NODES * DLAT;         // [80000,128] holds h
    int*   deg_out = (int*)(gat + (size_t)N_NODES * DLAT); // [80000]
    int*   cnt     = deg_out + N_NODES;                    // [80000] count->cursor->rsq_deg
    int*   rowptr  = cnt + N_NODES;                        // [80001]
    int*   csr_src = rowptr + N_NODES + 1;                 // [1e6]
    int*   blocksum = csr_src + N_EDGES;                   // [SCAN_NB]
    float* rsq_deg = (float*)cnt;

    // ---- CSR build (shared by both layers) ----
    hipMemsetAsync(deg_out, 0, N_NODES * sizeof(int), stream);
    hipMemsetAsync(cnt, 0, N_NODES * sizeof(int), stream);
    count_kernel<<<(N_EDGES + 255) / 256, 256, 0, stream>>>(src, dst, deg_out, cnt);
    scan_local_kernel<<<SCAN_NB, 256, 0, stream>>>(cnt, rowptr, blocksum);
    scan_blocksums_kernel<<<1, 512, 0, stream>>>(blocksum);
    scan_add_kernel<<<SCAN_NB, 256, 0, stream>>>(rowptr, blocksum);
    hipMemsetAsync(cnt, 0, N_NODES * sizeof(int), stream);
    csr_fill_kernel<<<(N_EDGES + 255) / 256, 256, 0, stream>>>(src, dst, rowptr, cnt, csr_src);
    deg_rsqrt_kernel<<<(N_NODES + 255) / 256, 256, 0, stream>>>(deg_out, rsq_deg);

    // ---- x = l2norm(concat(preference, tanh(features@mlp_w+b))) ----
    hipMemcpyAsync(x, pref, (size_t)NUM_USER * DLAT * sizeof(float),
                   hipMemcpyDeviceToDevice, stream);
    gemm_kernel<FEAT_DIM, DLAT, 1, true><<<(NUM_ITEM + 63) / 64, 256, 0, stream>>>(
        features, FEAT_DIM, mlp_w, mlp_b, x + (size_t)NUM_USER * DLAT, DLAT, NUM_ITEM);
    l2norm_rows_kernel<<<(N_NODES + 3) / 4, 256, 0, stream>>>(x);

    // ---- GAT layer 1 (D=128) ----
    gemm_kernel<DLAT, DLAT, 0, false><<<N_NODES / 64, 256, 0, stream>>>(
        x, DLAT, conv1_w, nullptr, xw, DLAT, N_NODES);
    gat_layer_kernel<DLAT><<<(N_NODES + 3) / 4, 256, 0, stream>>>(
        xw, rowptr, csr_src, rsq_deg, gat);
    combine_gemm_kernel<DLAT><<<N_NODES / 64, 256, 0, stream>>>(
        gat, x, DLAT, g1_w, g1_b, lin1_w, lin1_b, id_emb, out, 0);

    // ---- GAT layer 2 (D=64); x1 lives in out[:, :64] ----
    gemm_kernel<DID, DID, 0, false><<<N_NODES / 64, 256, 0, stream>>>(
        out, 2 * DID, conv2_w, nullptr, xw, DID, N_NODES);
    gat_layer_kernel<DID><<<(N_NODES + 3) / 4, 256, 0, stream>>>(
        xw, rowptr, csr_src, rsq_deg, gat);
    combine_gemm_kernel<DID><<<N_NODES / 64, 256, 0, stream>>>(
        gat, out, 2 * DID, g2_w, g2_b, lin2_w, lin2_b, id_emb, out, DID);
}

// Round 8
// 515.072 us; speedup vs baseline: 4.9529x; 1.0984x over previous
//
#include <hip/hip_runtime.h>
#include <hip/hip_bf16.h>
#include <math.h>

#define NUM_USER 50000
#define NUM_ITEM 30000
#define N_NODES  80000
#define N_EDGES  1000000
#define FEAT_DIM 768
#define DLAT 128
#define DID  64
#define NEG_SLOPE 0.01f

#define SCAN_NB ((N_NODES + 255) / 256)   // 313 blocks

__device__ __forceinline__ float leaky(float v) { return v >= 0.f ? v : NEG_SLOPE * v; }

__device__ __forceinline__ float wave_reduce_sum(float v) {
#pragma unroll
    for (int off = 32; off > 0; off >>= 1) v += __shfl_xor(v, off, 64);
    return v;
}

// f32 -> bf16 RNE and back
__device__ __forceinline__ unsigned short f2bf(float f) {
    unsigned int u = __float_as_uint(f);
    unsigned int r = u + 0x7fffu + ((u >> 16) & 1u);
    return (unsigned short)(r >> 16);
}
__device__ __forceinline__ float bf2f(unsigned short h) {
    return __uint_as_float(((unsigned int)h) << 16);
}

// =======================================================================
// Generic register-tiled GEMM (f32 vector path, for 128/64 shapes)
// =======================================================================
template<int K_TOTAL, int N_COLS, int ACT, bool HAS_BIAS>
__global__ __launch_bounds__(256) void gemm_kernel(
    const float* __restrict__ A, int lda,
    const float* __restrict__ W, const float* __restrict__ bias,
    float* __restrict__ O, int ldo, int rows)
{
    constexpr int KC = 64;
    constexpr int CT = N_COLS / 16;
    __shared__ float sW[KC * N_COLS];
    __shared__ float sX[64][KC + 4];

    const int tid = threadIdx.x;
    const int ty = tid >> 4;
    const int tx = tid & 15;
    const int r0 = blockIdx.x * 64;

    float acc[4][CT];
#pragma unroll
    for (int i = 0; i < 4; i++)
#pragma unroll
        for (int c = 0; c < CT; c++) acc[i][c] = 0.f;

    for (int kc = 0; kc < K_TOTAL; kc += KC) {
        const float4* Wc = (const float4*)(W + (size_t)kc * N_COLS);
        for (int i = tid; i < KC * N_COLS / 4; i += 256)
            ((float4*)sW)[i] = Wc[i];
        {
            int row = tid >> 2, q = tid & 3;
            int gr = r0 + row;
            float4 v[4];
            if (gr < rows) {
                const float4* Ar = (const float4*)(A + (size_t)gr * lda + kc);
#pragma unroll
                for (int i = 0; i < 4; i++) v[i] = Ar[q * 4 + i];
            } else {
#pragma unroll
                for (int i = 0; i < 4; i++) v[i] = make_float4(0.f, 0.f, 0.f, 0.f);
            }
#pragma unroll
            for (int i = 0; i < 4; i++)
                *(float4*)&sX[row][q * 16 + i * 4] = v[i];
        }
        __syncthreads();

        for (int k = 0; k < KC; k++) {
            float xv[4];
#pragma unroll
            for (int i = 0; i < 4; i++) xv[i] = sX[ty * 4 + i][k];
            float4 w0 = *(const float4*)&sW[k * N_COLS + tx * CT];
            if (CT == 8) {
                float4 w1 = *(const float4*)&sW[k * N_COLS + tx * CT + 4];
#pragma unroll
                for (int i = 0; i < 4; i++) {
                    acc[i][0] += xv[i] * w0.x; acc[i][1] += xv[i] * w0.y;
                    acc[i][2] += xv[i] * w0.z; acc[i][3] += xv[i] * w0.w;
                    acc[i][4] += xv[i] * w1.x; acc[i][5] += xv[i] * w1.y;
                    acc[i][6] += xv[i] * w1.z; acc[i][7] += xv[i] * w1.w;
                }
            } else {
#pragma unroll
                for (int i = 0; i < 4; i++) {
                    acc[i][0] += xv[i] * w0.x; acc[i][1] += xv[i] * w0.y;
                    acc[i][2] += xv[i] * w0.z; acc[i][3] += xv[i] * w0.w;
                }
            }
        }
        __syncthreads();
    }

#pragma unroll
    for (int i = 0; i < 4; i++) {
        int gr = r0 + ty * 4 + i;
        if (gr >= rows) continue;
#pragma unroll
        for (int c = 0; c < CT; c++) {
            int col = tx * CT + c;
            float v = acc[i][c];
            if (HAS_BIAS) v += bias[col];
            if (ACT == 1) v = tanhf(v);
            O[(size_t)gr * ldo + col] = v;
        }
    }
}

// =======================================================================
// MLP via split-bf16 MFMA: F@W ~= Fh@Wh + Fh@Wl + Fl@Wh (f32 accum).
// hi = bf16(v), lo = bf16(v - hi): ~16-bit effective mantissa.
// Block 64 rows x 128 cols, 4 waves 2x2; wave tile 32x64; K-chunk 64.
// Layouts: A row-major LDS (lane reads 8 contig k at row lane&15,
// k-half lane>>4); W^T likewise; C/D col=lane&15, row=(lane>>4)*4+reg.
// NOTE: xout is already offset to the item rows (launch passes x+NUM_USER*DLAT).
// =======================================================================
typedef __attribute__((ext_vector_type(8))) short short8v;
typedef __attribute__((ext_vector_type(4))) float f32x4;

__global__ __launch_bounds__(256) void wt_prep_kernel(
    const float* __restrict__ W, unsigned short* __restrict__ Wh,
    unsigned short* __restrict__ Wl)
{
    int id = blockIdx.x * 256 + threadIdx.x;     // over [128][768] output space
    if (id < FEAT_DIM * DLAT) {
        int n = id / FEAT_DIM, k = id % FEAT_DIM;
        float v = W[(size_t)k * DLAT + n];
        unsigned short h = f2bf(v);
        Wh[id] = h;
        Wl[id] = f2bf(v - bf2f(h));
    }
}

__global__ __launch_bounds__(256) void mlp_mfma_kernel(
    const float* __restrict__ F,
    const unsigned short* __restrict__ Wh, const unsigned short* __restrict__ Wl,
    const float* __restrict__ bias, float* __restrict__ xout)
{
    __shared__ unsigned short sAh[64][72];     // 9.2 KB each
    __shared__ unsigned short sAl[64][72];
    __shared__ unsigned short sWh[128][72];    // 18.4 KB each
    __shared__ unsigned short sWlo[128][72];

    const int tid = threadIdx.x;
    const int lane = tid & 63;
    const int w = tid >> 6;
    const int wr = w >> 1, wc = w & 1;
    const int r0 = blockIdx.x * 64;

    f32x4 acc[2][4];
#pragma unroll
    for (int m = 0; m < 2; m++)
#pragma unroll
        for (int n = 0; n < 4; n++) acc[m][n] = (f32x4){0.f, 0.f, 0.f, 0.f};

    for (int kc = 0; kc < FEAT_DIM; kc += 64) {
        // ---- stage A chunk 64x64 f32 -> bf16 hi/lo ----
#pragma unroll
        for (int it = 0; it < 2; it++) {
            int slot = tid + it * 256;           // 0..511
            int row = slot >> 3;
            int k8 = (slot & 7) * 8;
            int gr = r0 + row;
            float v[8];
#pragma unroll
            for (int i = 0; i < 8; i++) v[i] = 0.f;
            if (gr < NUM_ITEM) {
                const float4* p = (const float4*)(F + (size_t)gr * FEAT_DIM + kc + k8);
                float4 a = p[0], b = p[1];
                v[0]=a.x; v[1]=a.y; v[2]=a.z; v[3]=a.w;
                v[4]=b.x; v[5]=b.y; v[6]=b.z; v[7]=b.w;
            }
            unsigned int ph[4], pl[4];
#pragma unroll
            for (int i = 0; i < 4; i++) {
                unsigned short h0 = f2bf(v[2*i]),   l0 = f2bf(v[2*i]   - bf2f(h0));
                unsigned short h1 = f2bf(v[2*i+1]), l1 = f2bf(v[2*i+1] - bf2f(h1));
                ph[i] = (unsigned int)h0 | ((unsigned int)h1 << 16);
                pl[i] = (unsigned int)l0 | ((unsigned int)l1 << 16);
            }
            *(int4*)&sAh[row][k8] = make_int4((int)ph[0], (int)ph[1], (int)ph[2], (int)ph[3]);
            *(int4*)&sAl[row][k8] = make_int4((int)pl[0], (int)pl[1], (int)pl[2], (int)pl[3]);
        }
        // ---- stage W^T chunk 128x64 bf16 hi/lo (pre-transposed in global) ----
#pragma unroll
        for (int it = 0; it < 4; it++) {
            int slot = tid + it * 256;           // 0..1023
            int n = slot >> 3;
            int k8 = (slot & 7) * 8;
            *(int4*)&sWh[n][k8]  = *(const int4*)(Wh + (size_t)n * FEAT_DIM + kc + k8);
            *(int4*)&sWlo[n][k8] = *(const int4*)(Wl + (size_t)n * FEAT_DIM + kc + k8);
        }
        __syncthreads();

        // ---- MFMA: 2 k-steps of 32, 3 products each ----
#pragma unroll
        for (int k0 = 0; k0 < 64; k0 += 32) {
            int klane = k0 + (lane >> 4) * 8;
            short8v ah[2], al[2], bh[4], bl[4];
#pragma unroll
            for (int m = 0; m < 2; m++) {
                int row = wr * 32 + m * 16 + (lane & 15);
                ah[m] = *(const short8v*)&sAh[row][klane];
                al[m] = *(const short8v*)&sAl[row][klane];
            }
#pragma unroll
            for (int n = 0; n < 4; n++) {
                int col = wc * 64 + n * 16 + (lane & 15);
                bh[n] = *(const short8v*)&sWh[col][klane];
                bl[n] = *(const short8v*)&sWlo[col][klane];
            }
#pragma unroll
            for (int m = 0; m < 2; m++)
#pragma unroll
                for (int n = 0; n < 4; n++) {
                    acc[m][n] = __builtin_amdgcn_mfma_f32_16x16x32_bf16(ah[m], bh[n], acc[m][n], 0, 0, 0);
                    acc[m][n] = __builtin_amdgcn_mfma_f32_16x16x32_bf16(ah[m], bl[n], acc[m][n], 0, 0, 0);
                    acc[m][n] = __builtin_amdgcn_mfma_f32_16x16x32_bf16(al[m], bh[n], acc[m][n], 0, 0, 0);
                }
        }
        __syncthreads();
    }

    // ---- epilogue: tanh(acc + bias) -> xout rows gr (xout pre-offset to items) ----
#pragma unroll
    for (int m = 0; m < 2; m++) {
        int rbase = r0 + wr * 32 + m * 16 + (lane >> 4) * 4;
#pragma unroll
        for (int n = 0; n < 4; n++) {
            int col = wc * 64 + n * 16 + (lane & 15);
            float bv = bias[col];
#pragma unroll
            for (int q = 0; q < 4; q++) {
                int gr = rbase + q;
                if (gr < NUM_ITEM)
                    xout[(size_t)gr * DLAT + col] = tanhf(acc[m][n][q] + bv);
            }
        }
    }
}

// =======================================================================
// Fused combine: out[n][out_off+c] = leaky(h@g_w + g_b + leaky(x@lin_w + lin_b) + id)
// =======================================================================
template<int K>
__global__ __launch_bounds__(256) void combine_gemm_kernel(
    const float* __restrict__ H,
    const float* __restrict__ X, int ldx,
    const float* __restrict__ g_w, const float* __restrict__ g_b,
    const float* __restrict__ lin_w, const float* __restrict__ lin_b,
    const float* __restrict__ id_emb,
    float* __restrict__ out, int out_off)
{
    constexpr int KC = 64;
    __shared__ float sWg[KC * DID];
    __shared__ float sWl[KC * DID];
    __shared__ float sH[64][KC + 4];
    __shared__ float sX[64][KC + 4];

    const int tid = threadIdx.x;
    const int ty = tid >> 4;
    const int tx = tid & 15;
    const int r0 = blockIdx.x * 64;

    float accG[4][4], accL[4][4];
#pragma unroll
    for (int i = 0; i < 4; i++)
#pragma unroll
        for (int c = 0; c < 4; c++) { accG[i][c] = 0.f; accL[i][c] = 0.f; }

    for (int kc = 0; kc < K; kc += KC) {
        const float4* Wg = (const float4*)(g_w + (size_t)kc * DID);
        const float4* Wl = (const float4*)(lin_w + (size_t)kc * DID);
        for (int i = tid; i < KC * DID / 4; i += 256) {
            ((float4*)sWg)[i] = Wg[i];
            ((float4*)sWl)[i] = Wl[i];
        }
        {
            int row = tid >> 2, q = tid & 3;
            int gr = r0 + row;
            const float4* Hr = (const float4*)(H + (size_t)gr * K + kc);
            const float4* Xr = (const float4*)(X + (size_t)gr * ldx + kc);
#pragma unroll
            for (int i = 0; i < 4; i++) {
                *(float4*)&sH[row][q * 16 + i * 4] = Hr[q * 4 + i];
                *(float4*)&sX[row][q * 16 + i * 4] = Xr[q * 4 + i];
            }
        }
        __syncthreads();

        for (int k = 0; k < KC; k++) {
            float hv[4], xv[4];
#pragma unroll
            for (int i = 0; i < 4; i++) { hv[i] = sH[ty * 4 + i][k]; xv[i] = sX[ty * 4 + i][k]; }
            float4 wg = *(const float4*)&sWg[k * DID + tx * 4];
            float4 wl = *(const float4*)&sWl[k * DID + tx * 4];
#pragma unroll
            for (int i = 0; i < 4; i++) {
                accG[i][0] += hv[i] * wg.x; accG[i][1] += hv[i] * wg.y;
                accG[i][2] += hv[i] * wg.z; accG[i][3] += hv[i] * wg.w;
                accL[i][0] += xv[i] * wl.x; accL[i][1] += xv[i] * wl.y;
                accL[i][2] += xv[i] * wl.z; accL[i][3] += xv[i] * wl.w;
            }
        }
        __syncthreads();
    }

#pragma unroll
    for (int i = 0; i < 4; i++) {
        int gr = r0 + ty * 4 + i;
#pragma unroll
        for (int c = 0; c < 4; c++) {
            int col = tx * 4 + c;
            float xh = leaky(accL[i][c] + lin_b[col]) + id_emb[(size_t)gr * DID + col];
            float v = leaky(accG[i][c] + g_b[col] + xh);
            out[(size_t)gr * (2 * DID) + out_off + col] = v;
        }
    }
}

// ---------------- in-place row L2 normalize (D=128), wave per row ----------------
__global__ __launch_bounds__(256) void l2norm_rows_kernel(float* __restrict__ x)
{
    int wid = blockIdx.x * 4 + (threadIdx.x >> 6);
    if (wid >= N_NODES) return;
    int lane = threadIdx.x & 63;
    float* row = x + (size_t)wid * DLAT;
    float v0 = row[lane], v1 = row[lane + 64];
    float s = wave_reduce_sum(v0 * v0 + v1 * v1);
    float inv = 1.0f / fmaxf(sqrtf(s), 1e-12f);
    row[lane] = v0 * inv;
    row[lane + 64] = v1 * inv;
}

// ---------------- degree count ----------------
__global__ __launch_bounds__(256) void count_kernel(
    const int* __restrict__ src, const int* __restrict__ dst,
    int* __restrict__ deg_out, int* __restrict__ cnt_in)
{
    int e = blockIdx.x * 256 + threadIdx.x;
    if (e < N_EDGES) {
        atomicAdd(&deg_out[src[e]], 1);
        atomicAdd(&cnt_in[dst[e]], 1);
    }
}

// ---------------- 3-phase multi-block exclusive scan ----------------
__global__ __launch_bounds__(256) void scan_local_kernel(
    const int* __restrict__ cnt, int* __restrict__ rowptr, int* __restrict__ blocksum)
{
    __shared__ int wsum[4];
    int gid = blockIdx.x * 256 + threadIdx.x;
    int lane = threadIdx.x & 63, w = threadIdx.x >> 6;
    int orig = (gid < N_NODES) ? cnt[gid] : 0;
    int v = orig;
#pragma unroll
    for (int off = 1; off < 64; off <<= 1) {
        int u = __shfl_up(v, off, 64);
        if (lane >= off) v += u;
    }
    if (lane == 63) wsum[w] = v;
    __syncthreads();
    int woff = 0;
#pragma unroll
    for (int i = 0; i < 4; i++) woff += (i < w) ? wsum[i] : 0;
    if (gid < N_NODES) rowptr[gid] = v - orig + woff;
    if (threadIdx.x == 255) blocksum[blockIdx.x] = woff + v;
}

__global__ __launch_bounds__(512) void scan_blocksums_kernel(int* __restrict__ blocksum)
{
    __shared__ int s[512];
    int t = threadIdx.x;
    int orig = (t < SCAN_NB) ? blocksum[t] : 0;
    s[t] = orig;
    __syncthreads();
    for (int off = 1; off < 512; off <<= 1) {
        int u = (t >= off) ? s[t - off] : 0;
        __syncthreads();
        s[t] += u;
        __syncthreads();
    }
    if (t < SCAN_NB) blocksum[t] = s[t] - orig;
}

__global__ __launch_bounds__(256) void scan_add_kernel(
    int* __restrict__ rowptr, const int* __restrict__ blocksum)
{
    int gid = blockIdx.x * 256 + threadIdx.x;
    if (gid < N_NODES) rowptr[gid] += blocksum[blockIdx.x];
    if (gid == 0) rowptr[N_NODES] = N_EDGES;
}

// ---------------- CSR fill ----------------
__global__ __launch_bounds__(256) void csr_fill_kernel(
    const int* __restrict__ src, const int* __restrict__ dst,
    const int* __restrict__ rowptr, int* __restrict__ cursor, int* __restrict__ csr_src)
{
    int e = blockIdx.x * 256 + threadIdx.x;
    if (e < N_EDGES) {
        int d = dst[e];
        int slot = rowptr[d] + atomicAdd(&cursor[d], 1);
        csr_src[slot] = src[e];
    }
}

// ---------------- rsq_deg[n] = rsqrt(deg_out[n]) ----------------
__global__ __launch_bounds__(256) void deg_rsqrt_kernel(
    const int* __restrict__ deg_out, float* __restrict__ rsq)
{
    int n = blockIdx.x * 256 + threadIdx.x;
    if (n < N_NODES) rsq[n] = rsqrtf((float)deg_out[n]);
}

// =======================================================================
// Fused GAT layer, subgroup-parallel edges.
// =======================================================================
template<int D>
__global__ __launch_bounds__(256) void gat_layer_kernel(
    const float* __restrict__ xw, const int* __restrict__ rowptr,
    const int* __restrict__ csr_src, const float* __restrict__ rsq_deg,
    float* __restrict__ h)
{
    constexpr int SG  = D / 8;
    constexpr int EPC = 64 / SG;
    int wid = blockIdx.x * 4 + (threadIdx.x >> 6);
    if (wid >= N_NODES) return;
    const int lane = threadIdx.x & 63;
    const int g = lane / SG;
    const int t = lane % SG;
    const int start = rowptr[wid], end = rowptr[wid + 1];

    const float* xdp = xw + (size_t)wid * D + 8 * t;
    float4 xd0 = *(const float4*)(xdp);
    float4 xd1 = *(const float4*)(xdp + 4);

    float m = -1e30f, l = 0.f;
    float acc[8];
#pragma unroll
    for (int c = 0; c < 8; c++) acc[c] = 0.f;

    for (int base = start; base < end; base += EPC) {
        int i = base + g;
        bool valid = (i < end);
        int s = valid ? csr_src[i] : 0;
        const float* row = xw + (size_t)s * D + 8 * t;
        float4 a0 = *(const float4*)(row);
        float4 a1 = *(const float4*)(row + 4);
        float p = a0.x * xd0.x + a0.y * xd0.y + a0.z * xd0.z + a0.w * xd0.w
                + a1.x * xd1.x + a1.y * xd1.y + a1.z * xd1.z + a1.w * xd1.w;
#pragma unroll
        for (int off = SG / 2; off > 0; off >>= 1) p += __shfl_xor(p, off, 64);
        float rsd = valid ? rsq_deg[s] : 1.f;
        float gate = 1.0f / (1.0f + __expf(-(p * rsd)));
        float sc = valid ? p * gate : -1e30f;
        float mnew = fmaxf(m, sc);
        float scale = __expf(m - mnew);
        float w = valid ? __expf(sc - mnew) : 0.f;
        l = l * scale + w;
        acc[0] = acc[0] * scale + w * a0.x;
        acc[1] = acc[1] * scale + w * a0.y;
        acc[2] = acc[2] * scale + w * a0.z;
        acc[3] = acc[3] * scale + w * a0.w;
        acc[4] = acc[4] * scale + w * a1.x;
        acc[5] = acc[5] * scale + w * a1.y;
        acc[6] = acc[6] * scale + w * a1.z;
        acc[7] = acc[7] * scale + w * a1.w;
        m = mnew;
    }

    // merge subgroup states
#pragma unroll
    for (int off = SG; off < 64; off <<= 1) {
        float mo = __shfl_xor(m, off, 64);
        float lo = __shfl_xor(l, off, 64);
        float mnew = fmaxf(m, mo);
        float s1 = __expf(m - mnew), s2 = __expf(mo - mnew);
        l = l * s1 + lo * s2;
#pragma unroll
        for (int c = 0; c < 8; c++) {
            float ao = __shfl_xor(acc[c], off, 64);
            acc[c] = acc[c] * s1 + ao * s2;
        }
        m = mnew;
    }

    float invl = 1.0f / (l + 1e-16f);
    float ss = 0.f;
#pragma unroll
    for (int c = 0; c < 8; c++) { acc[c] *= invl; ss += acc[c] * acc[c]; }
#pragma unroll
    for (int off = SG / 2; off > 0; off >>= 1) ss += __shfl_xor(ss, off, 64);
    float inv = 1.0f / fmaxf(sqrtf(ss), 1e-12f);

    if (g == 0) {
        float4 o0, o1;
        o0.x = leaky(acc[0] * inv); o0.y = leaky(acc[1] * inv);
        o0.z = leaky(acc[2] * inv); o0.w = leaky(acc[3] * inv);
        o1.x = leaky(acc[4] * inv); o1.y = leaky(acc[5] * inv);
        o1.z = leaky(acc[6] * inv); o1.w = leaky(acc[7] * inv);
        float* op = h + (size_t)wid * D + 8 * t;
        *(float4*)(op) = o0;
        *(float4*)(op + 4) = o1;
    }
}

extern "C" void kernel_launch(void* const* d_in, const int* in_sizes, int n_in,
                              void* d_out, int out_size, void* d_ws, size_t ws_size,
                              hipStream_t stream)
{
    const float* features = (const float*)d_in[0];
    const float* id_emb   = (const float*)d_in[1];
    const int*   ei       = (const int*)d_in[2];
    const float* pref     = (const float*)d_in[3];
    const float* mlp_w    = (const float*)d_in[4];
    const float* mlp_b    = (const float*)d_in[5];
    const float* conv1_w  = (const float*)d_in[6];
    const float* lin1_w   = (const float*)d_in[7];
    const float* lin1_b   = (const float*)d_in[8];
    const float* g1_w     = (const float*)d_in[9];
    const float* g1_b     = (const float*)d_in[10];
    const float* conv2_w  = (const float*)d_in[11];
    const float* lin2_w   = (const float*)d_in[12];
    const float* lin2_b   = (const float*)d_in[13];
    const float* g2_w     = (const float*)d_in[14];
    const float* g2_b     = (const float*)d_in[15];
    const int* src = ei;
    const int* dst = ei + N_EDGES;
    float* out = (float*)d_out;

    // workspace layout (~128 MB)
    float* x       = (float*)d_ws;                         // [80000,128]
    float* xw      = x   + (size_t)N_NODES * DLAT;         // [80000,128]
    float* gat     = xw  + (size_t)N_NODES * DLAT;         // [80000,128] holds h
    int*   deg_out = (int*)(gat + (size_t)N_NODES * DLAT); // [80000]
    int*   cnt     = deg_out + N_NODES;                    // [80000] count->cursor->rsq_deg
    int*   rowptr  = cnt + N_NODES;                        // [80001]
    int*   csr_src = rowptr + N_NODES + 1;                 // [1e6]
    int*   blocksum = csr_src + N_EDGES;                   // [SCAN_NB]
    float* rsq_deg = (float*)cnt;
    // W hi/lo alias 'gat' (gat first written after mlp completes)
    unsigned short* Wh = (unsigned short*)gat;             // [128][768] bf16
    unsigned short* Wl = Wh + (size_t)FEAT_DIM * DLAT;     // [128][768] bf16

    // ---- CSR build (shared by both layers) ----
    hipMemsetAsync(deg_out, 0, N_NODES * sizeof(int), stream);
    hipMemsetAsync(cnt, 0, N_NODES * sizeof(int), stream);
    count_kernel<<<(N_EDGES + 255) / 256, 256, 0, stream>>>(src, dst, deg_out, cnt);
    scan_local_kernel<<<SCAN_NB, 256, 0, stream>>>(cnt, rowptr, blocksum);
    scan_blocksums_kernel<<<1, 512, 0, stream>>>(blocksum);
    scan_add_kernel<<<SCAN_NB, 256, 0, stream>>>(rowptr, blocksum);
    hipMemsetAsync(cnt, 0, N_NODES * sizeof(int), stream);
    csr_fill_kernel<<<(N_EDGES + 255) / 256, 256, 0, stream>>>(src, dst, rowptr, cnt, csr_src);
    deg_rsqrt_kernel<<<(N_NODES + 255) / 256, 256, 0, stream>>>(deg_out, rsq_deg);

    // ---- x = l2norm(concat(preference, tanh(features@mlp_w+b))) ----
    hipMemcpyAsync(x, pref, (size_t)NUM_USER * DLAT * sizeof(float),
                   hipMemcpyDeviceToDevice, stream);
    wt_prep_kernel<<<(FEAT_DIM * DLAT + 255) / 256, 256, 0, stream>>>(mlp_w, Wh, Wl);
    mlp_mfma_kernel<<<(NUM_ITEM + 63) / 64, 256, 0, stream>>>(
        features, Wh, Wl, mlp_b, x + (size_t)NUM_USER * DLAT);
    l2norm_rows_kernel<<<(N_NODES + 3) / 4, 256, 0, stream>>>(x);

    // ---- GAT layer 1 (D=128) ----
    gemm_kernel<DLAT, DLAT, 0, false><<<N_NODES / 64, 256, 0, stream>>>(
        x, DLAT, conv1_w, nullptr, xw, DLAT, N_NODES);
    gat_layer_kernel<DLAT><<<(N_NODES + 3) / 4, 256, 0, stream>>>(
        xw, rowptr, csr_src, rsq_deg, gat);
    combine_gemm_kernel<DLAT><<<N_NODES / 64, 256, 0, stream>>>(
        gat, x, DLAT, g1_w, g1_b, lin1_w, lin1_b, id_emb, out, 0);

    // ---- GAT layer 2 (D=64); x1 lives in out[:, :64] ----
    gemm_kernel<DID, DID, 0, false><<<N_NODES / 64, 256, 0, stream>>>(
        out, 2 * DID, conv2_w, nullptr, xw, DID, N_NODES);
    gat_layer_kernel<DID><<<(N_NODES + 3) / 4, 256, 0, stream>>>(
        xw, rowptr, csr_src, rsq_deg, gat);
    combine_gemm_kernel<DID><<<N_NODES / 64, 256, 0, stream>>>(
        gat, out, 2 * DID, g2_w, g2_b, lin2_w, lin2_b, id_emb, out, DID);
}